// Round 1
// baseline (849.648 us; speedup 1.0000x reference)
//
#include <hip/hip_runtime.h>
#include <hip/hip_bf16.h>

typedef unsigned short ushort_t;
typedef unsigned int uint_t;
typedef __attribute__((ext_vector_type(8))) short short8;
typedef __attribute__((ext_vector_type(4))) float f32x4;

#define DIMC 256
#define D_INNER 512
#define D_STATE 64
#define DT_RANK 16
#define LSEQ 4096
#define BS2 8            // 2*BS batches through mamba
#define MROWS (BS2*LSEQ) // 32768

__device__ __forceinline__ float b2f(ushort_t u) {
    union { uint_t i; float f; } v; v.i = ((uint_t)u) << 16; return v.f;
}
__device__ __forceinline__ ushort_t f2b(float f) {
    union { float f; uint_t i; } v; v.f = f;
    uint_t r = v.i + 0x7FFFu + ((v.i >> 16) & 1u);   // RNE
    return (ushort_t)(r >> 16);
}

// async global->LDS 16B per lane (HW: wave-uniform LDS base + lane*16)
typedef __attribute__((address_space(1))) const unsigned int gas_u32;
typedef __attribute__((address_space(3))) unsigned int las_u32;
__device__ __forceinline__ void gload16(const void* g, void* l) {
    __builtin_amdgcn_global_load_lds((gas_u32*)g, (las_u32*)l, 16, 0, 0);
}

// ---------------- fp32 -> bf16 conversion of the 3 MFMA weight mats ----------------
__global__ void cvtw3(const float* __restrict__ s0, ushort_t* __restrict__ d0,
                      const float* __restrict__ s1, ushort_t* __restrict__ d1,
                      const float* __restrict__ s2, ushort_t* __restrict__ d2) {
    int i = blockIdx.x * 256 + threadIdx.x;
    const int n0 = 1024 * 256, n1 = 144 * 512, n2 = 256 * 512;
    if (i < n0) d0[i] = f2b(s0[i]);
    else if (i < n0 + n1) d1[i - n0] = f2b(s1[i - n0]);
    else if (i < n0 + n1 + n2) d2[i - n0 - n1] = f2b(s2[i - n0 - n1]);
}

// ---------------- LN1 + build xm (both orders), fp32 in, bf16 out ----------------
__global__ void ln1_build_xm(const float* __restrict__ x,
                             const float* __restrict__ w,
                             const float* __restrict__ bb,
                             ushort_t* __restrict__ xm) {
    int row = blockIdx.x;            // b*4096 + l  (b in 0..3)
    int c = threadIdx.x;             // 0..255
    float v = x[(size_t)row * DIMC + c];
    float s1 = v, s2 = v * v;
    for (int off = 32; off; off >>= 1) {
        s1 += __shfl_xor(s1, off, 64);
        s2 += __shfl_xor(s2, off, 64);
    }
    __shared__ float sa[4], sb[4];
    int widx = c >> 6, lane = c & 63;
    if (lane == 0) { sa[widx] = s1; sb[widx] = s2; }
    __syncthreads();
    s1 = sa[0] + sa[1] + sa[2] + sa[3];
    s2 = sb[0] + sb[1] + sb[2] + sb[3];
    float mu = s1 * (1.0f / 256.0f);
    float var = s2 * (1.0f / 256.0f) - mu * mu;
    float xn = (v - mu) * rsqrtf(var + 1e-6f) * w[c] + bb[c];
    ushort_t o = f2b(xn);
    int b = row >> 12, l = row & 4095, i = l >> 6, j = l & 63;
    xm[((size_t)b * LSEQ + l) * DIMC + c] = o;
    xm[((size_t)(4 + b) * LSEQ + (j * 64 + i)) * DIMC + c] = o;
}

// ---------------- 128x128 LDS-tiled NT GEMM with global_load_lds staging ----------------
__global__ void __launch_bounds__(256, 4)
gemm128(const ushort_t* __restrict__ A,
        const ushort_t* __restrict__ W,
        ushort_t* __restrict__ C, int M, int N, int K) {
    __shared__ ushort_t Ash[128 * 32];
    __shared__ ushort_t Bsh[128 * 32];
    int tid = threadIdx.x;
    int lane = tid & 63, widx = tid >> 6;
    int wm = widx & 1, wn = widx >> 1;
    int l16 = lane & 15, quad = lane >> 4;
    int mblk = blockIdx.x * 128, nblk = blockIdx.y * 128;
    f32x4 acc[4][4];
    #pragma unroll
    for (int i = 0; i < 4; ++i)
        #pragma unroll
        for (int j = 0; j < 4; ++j)
            acc[i][j] = f32x4{0.0f, 0.0f, 0.0f, 0.0f};
    int srow = tid >> 2;
    int sseg = (tid & 3) * 8;
    bool jv[4];
    #pragma unroll
    for (int j = 0; j < 4; ++j) jv[j] = (nblk + wn * 64 + j * 16) < N;

    for (int k0 = 0; k0 < K; k0 += 32) {
        __syncthreads();
        #pragma unroll
        for (int q = 0; q < 2; ++q) {
            int row = q * 64 + srow;
            gload16(&A[(size_t)(mblk + row) * K + k0 + sseg], &Ash[row * 32 + sseg]);
            gload16(&W[(size_t)(nblk + row) * K + k0 + sseg], &Bsh[row * 32 + sseg]);
        }
        __syncthreads();
        short8 af[4], bf[4];
        #pragma unroll
        for (int i = 0; i < 4; ++i)
            af[i] = *(const short8*)&Ash[(wm * 64 + i * 16 + l16) * 32 + quad * 8];
        #pragma unroll
        for (int j = 0; j < 4; ++j)
            bf[j] = *(const short8*)&Bsh[(wn * 64 + j * 16 + l16) * 32 + quad * 8];
        #pragma unroll
        for (int i = 0; i < 4; ++i)
            #pragma unroll
            for (int j = 0; j < 4; ++j)
                if (jv[j])
                    acc[i][j] = __builtin_amdgcn_mfma_f32_16x16x32_bf16(af[i], bf[j], acc[i][j], 0, 0, 0);
    }
    #pragma unroll
    for (int i = 0; i < 4; ++i) {
        #pragma unroll
        for (int j = 0; j < 4; ++j) {
            if (!jv[j]) continue;
            int col = nblk + wn * 64 + j * 16 + l16;
            #pragma unroll
            for (int r = 0; r < 4; ++r) {
                int row = mblk + wm * 64 + i * 16 + quad * 4 + r;
                C[(size_t)row * N + col] = f2b(acc[i][j][r]);
            }
        }
    }
}

// ---------------- gemm128 variant: K=256, N=1024, split outputs at col 512 ----------------
__global__ void __launch_bounds__(256, 4)
gemm128_split(const ushort_t* __restrict__ A,
              const ushort_t* __restrict__ W,
              ushort_t* __restrict__ outX,   // cols 0..511
              ushort_t* __restrict__ outZ) { // cols 512..1023
    const int K = 256;
    __shared__ ushort_t Ash[128 * 32];
    __shared__ ushort_t Bsh[128 * 32];
    int tid = threadIdx.x;
    int lane = tid & 63, widx = tid >> 6;
    int wm = widx & 1, wn = widx >> 1;
    int l16 = lane & 15, quad = lane >> 4;
    int mblk = blockIdx.x * 128, nblk = blockIdx.y * 128;
    f32x4 acc[4][4];
    #pragma unroll
    for (int i = 0; i < 4; ++i)
        #pragma unroll
        for (int j = 0; j < 4; ++j)
            acc[i][j] = f32x4{0.0f, 0.0f, 0.0f, 0.0f};
    int srow = tid >> 2;
    int sseg = (tid & 3) * 8;
    for (int k0 = 0; k0 < K; k0 += 32) {
        __syncthreads();
        #pragma unroll
        for (int q = 0; q < 2; ++q) {
            int row = q * 64 + srow;
            gload16(&A[(size_t)(mblk + row) * K + k0 + sseg], &Ash[row * 32 + sseg]);
            gload16(&W[(size_t)(nblk + row) * K + k0 + sseg], &Bsh[row * 32 + sseg]);
        }
        __syncthreads();
        short8 af[4], bf[4];
        #pragma unroll
        for (int i = 0; i < 4; ++i)
            af[i] = *(const short8*)&Ash[(wm * 64 + i * 16 + l16) * 32 + quad * 8];
        #pragma unroll
        for (int j = 0; j < 4; ++j)
            bf[j] = *(const short8*)&Bsh[(wn * 64 + j * 16 + l16) * 32 + quad * 8];
        #pragma unroll
        for (int i = 0; i < 4; ++i)
            #pragma unroll
            for (int j = 0; j < 4; ++j)
                acc[i][j] = __builtin_amdgcn_mfma_f32_16x16x32_bf16(af[i], bf[j], acc[i][j], 0, 0, 0);
    }
    #pragma unroll
    for (int i = 0; i < 4; ++i) {
        #pragma unroll
        for (int j = 0; j < 4; ++j) {
            int colg = nblk + wn * 64 + j * 16 + l16;    // tile never straddles 512
            ushort_t* dst = (colg < 512) ? outX : outZ;
            int col = colg & 511;
            #pragma unroll
            for (int r = 0; r < 4; ++r) {
                int row = mblk + wm * 64 + i * 16 + quad * 4 + r;
                dst[(size_t)row * 512 + col] = f2b(acc[i][j][r]);
            }
        }
    }
}

// ---------------- tiled conv(4)+SiLU: all-coalesced, dual output ----------------
__global__ void conv_silu_t(const ushort_t* __restrict__ xh,
                            const float* __restrict__ cw,
                            const float* __restrict__ cb,
                            ushort_t* __restrict__ xc,
                            ushort_t* __restrict__ u_T) {
    int bt0 = blockIdx.x * 64;
    int d0  = blockIdx.y * 64;
    int b   = bt0 >> 12;
    int t0  = bt0 & 4095;
    __shared__ ushort_t tin[67][66];
    __shared__ ushort_t tout[64][66];
    int tid = threadIdx.x, lane = tid & 63, widx = tid >> 6;
    for (int r = widx; r < 67; r += 4) {
        int tt = t0 - 3 + r;
        tin[r][lane] = (tt >= 0) ? xh[((size_t)bt0 - 3 + r) * 512 + d0 + lane] : (ushort_t)0;
    }
    __syncthreads();
    for (int dd = widx; dd < 64; dd += 4) {
        int d = d0 + dd;
        float acc = cb[d];
        #pragma unroll
        for (int k = 0; k < 4; ++k)
            acc += cw[d * 4 + k] * b2f(tin[lane + k][dd]);
        float s = acc / (1.0f + __expf(-acc));
        ushort_t o = f2b(s);
        u_T[((size_t)b * 512 + d) * 4096 + t0 + lane] = o;
        tout[lane][dd] = o;
    }
    __syncthreads();
    for (int r = widx; r < 64; r += 4)
        xc[((size_t)bt0 + r) * 512 + d0 + lane] = tout[r][lane];
}

// ---------------- tiled dt/w (+fused B/C unpack on y==0 blocks) ----------------
__global__ void dt_sp_t(const ushort_t* __restrict__ xdbl,
                        const float* __restrict__ wdt,
                        const float* __restrict__ bdt,
                        const ushort_t* __restrict__ u_T,
                        ushort_t* __restrict__ dt_T,
                        ushort_t* __restrict__ w_T,
                        float2* __restrict__ BCf) {
    int bt0 = blockIdx.x * 64;
    int d0  = blockIdx.y * 64;
    int b   = bt0 >> 12;
    int t0  = bt0 & 4095;
    __shared__ float din[64][17];
    int tid = threadIdx.x;
    for (int i = tid; i < 64 * 16; i += 256) {
        int r = i >> 4, k = i & 15;
        din[r][k] = b2f(xdbl[((size_t)bt0 + r) * 144 + k]);
    }
    __syncthreads();
    int lane = tid & 63, widx = tid >> 6;
    for (int dd = widx; dd < 64; dd += 4) {
        int d = d0 + dd;
        float acc = bdt[d];
        #pragma unroll
        for (int k = 0; k < 16; ++k)
            acc += din[lane][k] * wdt[d * 16 + k];
        float sp = (acc > 20.0f) ? acc : log1pf(__expf(acc));
        size_t idx = ((size_t)b * 512 + d) * 4096 + t0 + lane;
        dt_T[idx] = f2b(sp);
        float uvv = b2f(u_T[idx]);
        w_T[idx] = f2b(sp * uvv);
    }
    // fused B/C unpack (one d-slice of blocks covers it; d-independent data)
    if (blockIdx.y == 0) {
        for (int i = tid; i < 64 * 64; i += 256) {
            size_t row = (size_t)bt0 + (i >> 6);
            int s = i & 63;
            const ushort_t* rp = xdbl + row * 144;
            BCf[(row << 6) + s] = make_float2(b2f(rp[16 + s]), b2f(rp[80 + s]));
        }
    }
}

// ---------------- selective scan v11 ----------------
// Changes vs v10:
//  - double-buffered 32-step half-slab B/C staging (2x16KB, same 32KB LDS):
//    gload_lds issued BEFORE each half's compute, so the compiler's forced
//    vmcnt(0) drain at the barrier lands after ~1800cy of compute (was: bare
//    drain = exposed latency every slab, the ~20% non-VALU-busy).
//  - y store deferred to the top of the next slab (store-ack overlapped).
//  - lvl0/1 merges: fused v_add_f32_dpp (3 VALU slots instead of 4).
//  - lvl4/5 merges: v_permlane16/32_swap_b32 + add (2 slots, no LDS permute).
template<int LVL>
__device__ __forceinline__ float merge_lvl_t(float left, float right, int lane) {
    bool bit = (lane >> LVL) & 1;
    float send = bit ? left : right;
    float keep = bit ? right : left;
    float out;
    if constexpr (LVL == 0) {
        asm volatile("s_nop 1\n\t"
                     "v_add_f32_dpp %0, %1, %2 quad_perm:[1,0,3,2] row_mask:0xf bank_mask:0xf"
                     : "=v"(out) : "v"(send), "v"(keep));
    } else if constexpr (LVL == 1) {
        asm volatile("s_nop 1\n\t"
                     "v_add_f32_dpp %0, %1, %2 quad_perm:[2,3,0,1] row_mask:0xf bank_mask:0xf"
                     : "=v"(out) : "v"(send), "v"(keep));
    } else {
        float recv = __shfl_xor(send, 1 << LVL, 64);
        out = keep + recv;
    }
    return out;
}
// lvl4 merge: rows(16) of `a` interleave-sum with rows of `b`:
// result row0: a.r0+a.r1, row1: b.r0+b.r1, row2: a.r2+a.r3, row3: b.r2+b.r3
// == exact placement of the old cndmask+shfl_xor16 merge.
__device__ __forceinline__ float merge16_swap(float a, float b) {
    asm volatile("s_nop 1\n\tv_permlane16_swap_b32 %0, %1" : "+v"(a), "+v"(b));
    return a + b;
}
// lvl5 merge: lanes<32: a[i]+a[i+32]; lanes>=32: b[i]+b[i^32]
__device__ __forceinline__ float merge32_swap(float a, float b) {
    asm volatile("s_nop 1\n\tv_permlane32_swap_b32 %0, %1" : "+v"(a), "+v"(b));
    return a + b;
}

__global__ void __launch_bounds__(256, 4)
scan11(const ushort_t* __restrict__ dt_T,
       ushort_t* uT_ysT,
       const ushort_t* __restrict__ w_T,
       const float2* __restrict__ BCf,
       const float* __restrict__ Alog,
       const float* __restrict__ Dp) {
    __shared__ float2 BCsh[2][32][64];   // double-buffered half-slabs, 2x16KB
    int tid = threadIdx.x;
    int lane = tid & 63, widx = tid >> 6;
    int wid = blockIdx.x * 4 + widx;
    int b = wid >> 9, d = wid & 511;
    float a2 = -__expf(Alog[d * 64 + lane]) * 1.442695041f;   // log2(e) folded
    float Dd = Dp[d];
    float h = 0.0f;
    size_t rowT = ((size_t)b * 512 + d) * 4096;
    uint_t rowTu = __builtin_amdgcn_readfirstlane((uint_t)rowT);
    size_t base = (size_t)b * LSEQ;
    const uint_t* dtw = (const uint_t*)(dt_T + rowTu);
    const uint_t* wwp = (const uint_t*)(w_T + rowTu);

    // stage half-slab hs (32 timesteps = 16KB) into BCsh[bufi]
    auto STAGE = [&](int bufi, int hs) {
        const char* gsrc = (const char*)(BCf + (((size_t)(base + hs * 32)) << 6));
        char* ldst = (char*)&BCsh[bufi][0][0];
        size_t woff = (size_t)widx * 4096;       // 16KB / 4 waves
        #pragma unroll
        for (int it = 0; it < 4; ++it) {
            size_t o = woff + (size_t)it * 1024 + (size_t)lane * 16;
            gload16(gsrc + o, ldst + o);
        }
    };

    float acc[4];
    // 16 sequential steps; returns the fully-lvl0..3-merged v16
    auto STEP16 = [&](int bufi, int jbase, int dwb) -> float {
        float v16 = 0.0f;
        #pragma unroll
        for (int jj = 0; jj < 16; ++jj) {
            uint_t pd = dtw[dwb + (jj >> 1)];
            uint_t pw = wwp[dwb + (jj >> 1)];
            float sdt = __uint_as_float((jj & 1) ? (pd & 0xFFFF0000u) : (pd << 16));
            float sw  = __uint_as_float((jj & 1) ? (pw & 0xFFFF0000u) : (pw << 16));
            float2 bc = BCsh[bufi][jbase + jj][lane];     // single ds_read_b64
            float dA = __builtin_amdgcn_exp2f(sdt * a2);  // raw v_exp_f32
            h = dA * h + sw * bc.x;
            float v = h * bc.y;
            const int dest = (jj == 15) ? 4 : __builtin_ctz(~(unsigned)jj);
            if (0 < dest) v = merge_lvl_t<0>(acc[0], v, lane);
            if (1 < dest) v = merge_lvl_t<1>(acc[1], v, lane);
            if (2 < dest) v = merge_lvl_t<2>(acc[2], v, lane);
            if (3 < dest) v = merge_lvl_t<3>(acc[3], v, lane);
            if (jj == 15) v16 = v;
            else acc[dest] = v;
        }
        return v16;
    };

    STAGE(0, 0);
    __syncthreads();                 // prologue drain
    ushort_t ypend = 0;
    #pragma unroll 1
    for (int sl = 0; sl < 64; ++sl) {
        int t0 = sl * 64;
        int dwb = sl * 32;
        // ---- even half: compute steps t0..t0+31 from buf0 ----
        STAGE(1, 2 * sl + 1);                          // overlap with compute below
        if (sl) uT_ysT[rowT + t0 - 64 + lane] = ypend; // deferred y store (ack overlapped)
        float uvv = b2f(uT_ysT[rowT + t0 + lane]);     // u for this 64-slab
        float s4 = STEP16(0, 0, dwb);
        float s5 = merge16_swap(s4, STEP16(0, 16, dwb + 8));
        __syncthreads();   // compiler drains vmcnt here -> buf1 ready, buf0 free
        // ---- odd half: compute steps t0+32..t0+63 from buf1 ----
        if (sl + 1 < 64) STAGE(0, 2 * sl + 2);         // overlap with compute below
        float s4b = STEP16(1, 0, dwb + 16);
        float m = merge16_swap(s4b, STEP16(1, 16, dwb + 24));
        float yfin = merge32_swap(s5, m);
        ypend = f2b(yfin + uvv * Dd);
        __syncthreads();   // drain -> buf0 ready, buf1 free
    }
    uT_ysT[rowT + LSEQ - 64 + lane] = ypend;           // final slab's y
}

// ---------------- gate + transpose: ys[bt,d] = ysT[b,d,t] * silu(z[bt,d]) ----------------
__global__ void gate_t(const ushort_t* __restrict__ ysT,
                       const ushort_t* __restrict__ zb,
                       ushort_t* __restrict__ ys) {
    int bt0 = blockIdx.x * 64;
    int d0  = blockIdx.y * 64;
    int b   = bt0 >> 12;
    int t0  = bt0 & 4095;
    __shared__ ushort_t tile[64][66];
    int tid = threadIdx.x, lane = tid & 63, widx = tid >> 6;
    for (int dd = widx; dd < 64; dd += 4)
        tile[dd][lane] = ysT[((size_t)b * 512 + d0 + dd) * 4096 + t0 + lane];
    __syncthreads();
    for (int r = widx; r < 64; r += 4) {
        float zv = b2f(zb[((size_t)bt0 + r) * 512 + d0 + lane]);
        float yv = b2f(tile[lane][r]);
        float g = zv / (1.0f + __expf(-zv));
        ys[((size_t)bt0 + r) * 512 + d0 + lane] = f2b(yv * g);
    }
}

// ---------------- final LN + transpose-combine + residual (fp32 out) ----------------
__global__ void final_ln_add(const ushort_t* __restrict__ outm,
                             const float* __restrict__ x,
                             const float* __restrict__ w,
                             const float* __restrict__ bb,
                             float* __restrict__ out) {
    int row = blockIdx.x;
    int c = threadIdx.x;
    int b = row >> 12, l = row & 4095, i = l >> 6, j = l & 63;
    size_t rA = ((size_t)b * LSEQ + l) * DIMC;
    size_t rB = ((size_t)(4 + b) * LSEQ + (j * 64 + i)) * DIMC;
    float va = b2f(outm[rA + c]);
    float vb = b2f(outm[rB + c]);
    float s1 = va, s2 = va * va, s3 = vb, s4 = vb * vb;
    for (int off = 32; off; off >>= 1) {
        s1 += __shfl_xor(s1, off, 64);
        s2 += __shfl_xor(s2, off, 64);
        s3 += __shfl_xor(s3, off, 64);
        s4 += __shfl_xor(s4, off, 64);
    }
    __shared__ float sm[4][4];
    int widx = c >> 6, lane = c & 63;
    if (lane == 0) { sm[widx][0] = s1; sm[widx][1] = s2; sm[widx][2] = s3; sm[widx][3] = s4; }
    __syncthreads();
    s1 = sm[0][0] + sm[1][0] + sm[2][0] + sm[3][0];
    s2 = sm[0][1] + sm[1][1] + sm[2][1] + sm[3][1];
    s3 = sm[0][2] + sm[1][2] + sm[2][2] + sm[3][2];
    s4 = sm[0][3] + sm[1][3] + sm[2][3] + sm[3][3];
    float muA = s1 * (1.0f / 256.0f), varA = s2 * (1.0f / 256.0f) - muA * muA;
    float muB = s3 * (1.0f / 256.0f), varB = s4 * (1.0f / 256.0f) - muB * muB;
    float lw = w[c], lb = bb[c];
    float ya = (va - muA) * rsqrtf(varA + 1e-6f) * lw + lb;
    float yb = (vb - muB) * rsqrtf(varB + 1e-6f) * lw + lb;
    float xo = x[(size_t)row * DIMC + c];
    out[(size_t)row * DIMC + c] = xo + ya + yb;
}

extern "C" void kernel_launch(void* const* d_in, const int* in_sizes, int n_in,
                              void* d_out, int out_size, void* d_ws, size_t ws_size,
                              hipStream_t stream) {
    const float* x      = (const float*)d_in[0];
    const float* ln1_w  = (const float*)d_in[1];
    const float* ln1_b  = (const float*)d_in[2];
    const float* ln2_w  = (const float*)d_in[3];
    const float* ln2_b  = (const float*)d_in[4];
    const float* W_in   = (const float*)d_in[5];
    const float* conv_w = (const float*)d_in[6];
    const float* conv_b = (const float*)d_in[7];
    const float* W_x    = (const float*)d_in[8];
    const float* W_dt   = (const float*)d_in[9];
    const float* b_dt   = (const float*)d_in[10];
    const float* A_log  = (const float*)d_in[11];
    const float* D_par  = (const float*)d_in[12];
    const float* W_out  = (const float*)d_in[13];
    float* out = (float*)d_out;

    // ---- workspace (~169 MB) ----
    char* ws = (char*)d_ws;
    size_t off = 0;
    ushort_t* wb_in  = (ushort_t*)(ws + off); off += (size_t)1024 * 256 * 2;
    ushort_t* wb_x   = (ushort_t*)(ws + off); off += (size_t)144 * 512 * 2;
    ushort_t* wb_out = (ushort_t*)(ws + off); off += (size_t)256 * 512 * 2;
    const size_t R0 = (size_t)MROWS * DIMC * 2;
    const size_t R1 = (size_t)MROWS * 512 * 2;
    ushort_t* r0 = (ushort_t*)(ws + off); off += R0;   // xm -> xdbl -> outm
    ushort_t* r1 = (ushort_t*)(ws + off); off += R1;   // xhalf -> dt_T
    ushort_t* r2 = (ushort_t*)(ws + off); off += R1;   // z
    ushort_t* r3 = (ushort_t*)(ws + off); off += R1;   // xc -> w_T -> ys
    ushort_t* r4 = (ushort_t*)(ws + off); off += R1;   // u_T -> ysT (in place)
    float2*   BCf = (float2*)(ws + off);  off += (size_t)MROWS * 64 * 8;  // 16.8 MB

    ushort_t* xm    = r0;
    ushort_t* xdbl  = r0;
    ushort_t* outm  = r0;
    ushort_t* xhalf = r1;
    ushort_t* dt_T  = r1;
    ushort_t* zb    = r2;
    ushort_t* xc    = r3;
    ushort_t* w_T   = r3;
    ushort_t* ys    = r3;
    ushort_t* u_T   = r4;

    // 0. convert MFMA weights fp32 -> bf16 (one launch)
    const int ncvt = 1024 * 256 + 144 * 512 + 256 * 512;
    hipLaunchKernelGGL(cvtw3, dim3((ncvt + 255) / 256), dim3(256), 0, stream,
                       W_in, wb_in, W_x, wb_x, W_out, wb_out);

    // A. LayerNorm + dual-order xm
    hipLaunchKernelGGL(ln1_build_xm, dim3(4 * LSEQ), dim3(256), 0, stream,
                       x, ln1_w, ln1_b, xm);
    // B. one launch: cols<512 -> xhalf, cols>=512 -> zb
    hipLaunchKernelGGL(gemm128_split, dim3(MROWS / 128, 8), dim3(256), 0, stream,
                       xm, wb_in, xhalf, zb);
    // C. tiled conv + SiLU: xhalf -> xc[bt,d] + u_T[b,d,t]
    hipLaunchKernelGGL(conv_silu_t, dim3(MROWS / 64, 8), dim3(256), 0, stream,
                       xhalf, conv_w, conv_b, xc, u_T);
    // D. x_dbl = xc @ W_x^T   (N=144, K=512)
    hipLaunchKernelGGL(gemm128, dim3(MROWS / 128, 2), dim3(256), 0, stream,
                       xc, wb_x, xdbl, MROWS, 144, 512);
    // E. dt_T = softplus(...), w_T = dt*u, + fused B/C fp32 unpack
    hipLaunchKernelGGL(dt_sp_t, dim3(MROWS / 64, 8), dim3(256), 0, stream,
                       xdbl, W_dt, b_dt, u_T, dt_T, w_T, BCf);
    // F. selective scan v11: u_T -> ysT in place
    hipLaunchKernelGGL(scan11, dim3(BS2 * 512 / 4), dim3(256), 0, stream,
                       dt_T, u_T, w_T, BCf, A_log, D_par);
    // G. gate + transpose: ys[bt,d] = ysT * silu(z)
    hipLaunchKernelGGL(gate_t, dim3(MROWS / 64, 8), dim3(256), 0, stream,
                       u_T, zb, ys);
    // H. outm = ys @ W_out^T   (N=256, K=512)
    hipLaunchKernelGGL(gemm128, dim3(MROWS / 128, 2), dim3(256), 0, stream,
                       ys, wb_out, outm, MROWS, 256, 512);
    // I. final LN + transpose combine + residual (fp32 out)
    hipLaunchKernelGGL(final_ln_add, dim3(4 * LSEQ), dim3(256), 0, stream,
                       outm, x, ln2_w, ln2_b, out);
}

// Round 2
// 725.850 us; speedup vs baseline: 1.1706x; 1.1706x over previous
//
#include <hip/hip_runtime.h>
#include <hip/hip_bf16.h>

typedef unsigned short ushort_t;
typedef unsigned int uint_t;
typedef __attribute__((ext_vector_type(8))) short short8;
typedef __attribute__((ext_vector_type(4))) float f32x4;

#define DIMC 256
#define D_INNER 512
#define D_STATE 64
#define DT_RANK 16
#define LSEQ 4096
#define BS2 8            // 2*BS batches through mamba
#define MROWS (BS2*LSEQ) // 32768

__device__ __forceinline__ float b2f(ushort_t u) {
    union { uint_t i; float f; } v; v.i = ((uint_t)u) << 16; return v.f;
}
__device__ __forceinline__ ushort_t f2b(float f) {
    union { float f; uint_t i; } v; v.f = f;
    uint_t r = v.i + 0x7FFFu + ((v.i >> 16) & 1u);   // RNE
    return (ushort_t)(r >> 16);
}

// async global->LDS 16B per lane (HW: wave-uniform LDS base + lane*16)
typedef __attribute__((address_space(1))) const unsigned int gas_u32;
typedef __attribute__((address_space(3))) unsigned int las_u32;
__device__ __forceinline__ void gload16(const void* g, void* l) {
    __builtin_amdgcn_global_load_lds((gas_u32*)g, (las_u32*)l, 16, 0, 0);
}

// ---------------- fp32 -> bf16 conversion of the 3 MFMA weight mats ----------------
__global__ void cvtw3(const float* __restrict__ s0, ushort_t* __restrict__ d0,
                      const float* __restrict__ s1, ushort_t* __restrict__ d1,
                      const float* __restrict__ s2, ushort_t* __restrict__ d2) {
    int i = blockIdx.x * 256 + threadIdx.x;
    const int n0 = 1024 * 256, n1 = 144 * 512, n2 = 256 * 512;
    if (i < n0) d0[i] = f2b(s0[i]);
    else if (i < n0 + n1) d1[i - n0] = f2b(s1[i - n0]);
    else if (i < n0 + n1 + n2) d2[i - n0 - n1] = f2b(s2[i - n0 - n1]);
}

// ---------------- LN1 + build xm (both orders), fp32 in, bf16 out ----------------
__global__ void ln1_build_xm(const float* __restrict__ x,
                             const float* __restrict__ w,
                             const float* __restrict__ bb,
                             ushort_t* __restrict__ xm) {
    int row = blockIdx.x;            // b*4096 + l  (b in 0..3)
    int c = threadIdx.x;             // 0..255
    float v = x[(size_t)row * DIMC + c];
    float s1 = v, s2 = v * v;
    for (int off = 32; off; off >>= 1) {
        s1 += __shfl_xor(s1, off, 64);
        s2 += __shfl_xor(s2, off, 64);
    }
    __shared__ float sa[4], sb[4];
    int widx = c >> 6, lane = c & 63;
    if (lane == 0) { sa[widx] = s1; sb[widx] = s2; }
    __syncthreads();
    s1 = sa[0] + sa[1] + sa[2] + sa[3];
    s2 = sb[0] + sb[1] + sb[2] + sb[3];
    float mu = s1 * (1.0f / 256.0f);
    float var = s2 * (1.0f / 256.0f) - mu * mu;
    float xn = (v - mu) * rsqrtf(var + 1e-6f) * w[c] + bb[c];
    ushort_t o = f2b(xn);
    int b = row >> 12, l = row & 4095, i = l >> 6, j = l & 63;
    xm[((size_t)b * LSEQ + l) * DIMC + c] = o;
    xm[((size_t)(4 + b) * LSEQ + (j * 64 + i)) * DIMC + c] = o;
}

// ---------------- 128x128 LDS-tiled NT GEMM with global_load_lds staging ----------------
__global__ void __launch_bounds__(256, 4)
gemm128(const ushort_t* __restrict__ A,
        const ushort_t* __restrict__ W,
        ushort_t* __restrict__ C, int M, int N, int K) {
    __shared__ ushort_t Ash[128 * 32];
    __shared__ ushort_t Bsh[128 * 32];
    int tid = threadIdx.x;
    int lane = tid & 63, widx = tid >> 6;
    int wm = widx & 1, wn = widx >> 1;
    int l16 = lane & 15, quad = lane >> 4;
    int mblk = blockIdx.x * 128, nblk = blockIdx.y * 128;
    f32x4 acc[4][4];
    #pragma unroll
    for (int i = 0; i < 4; ++i)
        #pragma unroll
        for (int j = 0; j < 4; ++j)
            acc[i][j] = f32x4{0.0f, 0.0f, 0.0f, 0.0f};
    int srow = tid >> 2;
    int sseg = (tid & 3) * 8;
    bool jv[4];
    #pragma unroll
    for (int j = 0; j < 4; ++j) jv[j] = (nblk + wn * 64 + j * 16) < N;

    for (int k0 = 0; k0 < K; k0 += 32) {
        __syncthreads();
        #pragma unroll
        for (int q = 0; q < 2; ++q) {
            int row = q * 64 + srow;
            gload16(&A[(size_t)(mblk + row) * K + k0 + sseg], &Ash[row * 32 + sseg]);
            gload16(&W[(size_t)(nblk + row) * K + k0 + sseg], &Bsh[row * 32 + sseg]);
        }
        __syncthreads();
        short8 af[4], bf[4];
        #pragma unroll
        for (int i = 0; i < 4; ++i)
            af[i] = *(const short8*)&Ash[(wm * 64 + i * 16 + l16) * 32 + quad * 8];
        #pragma unroll
        for (int j = 0; j < 4; ++j)
            bf[j] = *(const short8*)&Bsh[(wn * 64 + j * 16 + l16) * 32 + quad * 8];
        #pragma unroll
        for (int i = 0; i < 4; ++i)
            #pragma unroll
            for (int j = 0; j < 4; ++j)
                if (jv[j])
                    acc[i][j] = __builtin_amdgcn_mfma_f32_16x16x32_bf16(af[i], bf[j], acc[i][j], 0, 0, 0);
    }
    #pragma unroll
    for (int i = 0; i < 4; ++i) {
        #pragma unroll
        for (int j = 0; j < 4; ++j) {
            if (!jv[j]) continue;
            int col = nblk + wn * 64 + j * 16 + l16;
            #pragma unroll
            for (int r = 0; r < 4; ++r) {
                int row = mblk + wm * 64 + i * 16 + quad * 4 + r;
                C[(size_t)row * N + col] = f2b(acc[i][j][r]);
            }
        }
    }
}

// ---------------- gemm128 variant: K=256, N=1024, split outputs at col 512 ----------------
__global__ void __launch_bounds__(256, 4)
gemm128_split(const ushort_t* __restrict__ A,
              const ushort_t* __restrict__ W,
              ushort_t* __restrict__ outX,   // cols 0..511
              ushort_t* __restrict__ outZ) { // cols 512..1023
    const int K = 256;
    __shared__ ushort_t Ash[128 * 32];
    __shared__ ushort_t Bsh[128 * 32];
    int tid = threadIdx.x;
    int lane = tid & 63, widx = tid >> 6;
    int wm = widx & 1, wn = widx >> 1;
    int l16 = lane & 15, quad = lane >> 4;
    int mblk = blockIdx.x * 128, nblk = blockIdx.y * 128;
    f32x4 acc[4][4];
    #pragma unroll
    for (int i = 0; i < 4; ++i)
        #pragma unroll
        for (int j = 0; j < 4; ++j)
            acc[i][j] = f32x4{0.0f, 0.0f, 0.0f, 0.0f};
    int srow = tid >> 2;
    int sseg = (tid & 3) * 8;
    for (int k0 = 0; k0 < K; k0 += 32) {
        __syncthreads();
        #pragma unroll
        for (int q = 0; q < 2; ++q) {
            int row = q * 64 + srow;
            gload16(&A[(size_t)(mblk + row) * K + k0 + sseg], &Ash[row * 32 + sseg]);
            gload16(&W[(size_t)(nblk + row) * K + k0 + sseg], &Bsh[row * 32 + sseg]);
        }
        __syncthreads();
        short8 af[4], bf[4];
        #pragma unroll
        for (int i = 0; i < 4; ++i)
            af[i] = *(const short8*)&Ash[(wm * 64 + i * 16 + l16) * 32 + quad * 8];
        #pragma unroll
        for (int j = 0; j < 4; ++j)
            bf[j] = *(const short8*)&Bsh[(wn * 64 + j * 16 + l16) * 32 + quad * 8];
        #pragma unroll
        for (int i = 0; i < 4; ++i)
            #pragma unroll
            for (int j = 0; j < 4; ++j)
                acc[i][j] = __builtin_amdgcn_mfma_f32_16x16x32_bf16(af[i], bf[j], acc[i][j], 0, 0, 0);
    }
    #pragma unroll
    for (int i = 0; i < 4; ++i) {
        #pragma unroll
        for (int j = 0; j < 4; ++j) {
            int colg = nblk + wn * 64 + j * 16 + l16;    // tile never straddles 512
            ushort_t* dst = (colg < 512) ? outX : outZ;
            int col = colg & 511;
            #pragma unroll
            for (int r = 0; r < 4; ++r) {
                int row = mblk + wm * 64 + i * 16 + quad * 4 + r;
                dst[(size_t)row * 512 + col] = f2b(acc[i][j][r]);
            }
        }
    }
}

// ---------------- tiled conv(4)+SiLU: all-coalesced, dual output ----------------
__global__ void conv_silu_t(const ushort_t* __restrict__ xh,
                            const float* __restrict__ cw,
                            const float* __restrict__ cb,
                            ushort_t* __restrict__ xc,
                            ushort_t* __restrict__ u_T) {
    int bt0 = blockIdx.x * 64;
    int d0  = blockIdx.y * 64;
    int b   = bt0 >> 12;
    int t0  = bt0 & 4095;
    __shared__ ushort_t tin[67][66];
    __shared__ ushort_t tout[64][66];
    int tid = threadIdx.x, lane = tid & 63, widx = tid >> 6;
    for (int r = widx; r < 67; r += 4) {
        int tt = t0 - 3 + r;
        tin[r][lane] = (tt >= 0) ? xh[((size_t)bt0 - 3 + r) * 512 + d0 + lane] : (ushort_t)0;
    }
    __syncthreads();
    for (int dd = widx; dd < 64; dd += 4) {
        int d = d0 + dd;
        float acc = cb[d];
        #pragma unroll
        for (int k = 0; k < 4; ++k)
            acc += cw[d * 4 + k] * b2f(tin[lane + k][dd]);
        float s = acc / (1.0f + __expf(-acc));
        ushort_t o = f2b(s);
        u_T[((size_t)b * 512 + d) * 4096 + t0 + lane] = o;
        tout[lane][dd] = o;
    }
    __syncthreads();
    for (int r = widx; r < 64; r += 4)
        xc[((size_t)bt0 + r) * 512 + d0 + lane] = tout[r][lane];
}

// ---------------- tiled dt/w (+fused B/C unpack on y==0 blocks) ----------------
__global__ void dt_sp_t(const ushort_t* __restrict__ xdbl,
                        const float* __restrict__ wdt,
                        const float* __restrict__ bdt,
                        const ushort_t* __restrict__ u_T,
                        ushort_t* __restrict__ dt_T,
                        ushort_t* __restrict__ w_T,
                        float2* __restrict__ BCf) {
    int bt0 = blockIdx.x * 64;
    int d0  = blockIdx.y * 64;
    int b   = bt0 >> 12;
    int t0  = bt0 & 4095;
    __shared__ float din[64][17];
    int tid = threadIdx.x;
    for (int i = tid; i < 64 * 16; i += 256) {
        int r = i >> 4, k = i & 15;
        din[r][k] = b2f(xdbl[((size_t)bt0 + r) * 144 + k]);
    }
    __syncthreads();
    int lane = tid & 63, widx = tid >> 6;
    for (int dd = widx; dd < 64; dd += 4) {
        int d = d0 + dd;
        float acc = bdt[d];
        #pragma unroll
        for (int k = 0; k < 16; ++k)
            acc += din[lane][k] * wdt[d * 16 + k];
        float sp = (acc > 20.0f) ? acc : log1pf(__expf(acc));
        size_t idx = ((size_t)b * 512 + d) * 4096 + t0 + lane;
        dt_T[idx] = f2b(sp);
        float uvv = b2f(u_T[idx]);
        w_T[idx] = f2b(sp * uvv);
    }
    // fused B/C unpack (one d-slice of blocks covers it; d-independent data)
    if (blockIdx.y == 0) {
        for (int i = tid; i < 64 * 64; i += 256) {
            size_t row = (size_t)bt0 + (i >> 6);
            int s = i & 63;
            const ushort_t* rp = xdbl + row * 144;
            BCf[(row << 6) + s] = make_float2(b2f(rp[16 + s]), b2f(rp[80 + s]));
        }
    }
}

// ---------------- selective scan v12: v10 structure + T14 async-STAGE split ----------------
// v10 cadence preserved (one 32KB stage per 64-step slab, 2 barriers/slab, same
// inter-block L2 pacing). Change: next slab's BCf is issued as 8x
// global_load_dwordx4 -> registers at the TOP of the current slab's compute
// (~1500cy in flight), then ds_write_b128'd after the read barrier. The forced
// vmcnt(0)-before-barrier now lands after the full compute phase instead of
// draining with zero compute in flight. Merges: v10 builtin forms (compiler
// fuses update_dpp+add and handles DPP hazards itself — v11's inline asm did
// not and stalled).
template<int LVL>
__device__ __forceinline__ float merge_lvl_t(float left, float right, int lane) {
    bool bit = (lane >> LVL) & 1;
    float send = bit ? left : right;
    float keep = bit ? right : left;
    float recv;
    if constexpr (LVL == 0)
        recv = __int_as_float(__builtin_amdgcn_update_dpp(
            0, __float_as_int(send), 0xB1, 0xF, 0xF, false));   // quad_perm xor1
    else if constexpr (LVL == 1)
        recv = __int_as_float(__builtin_amdgcn_update_dpp(
            0, __float_as_int(send), 0x4E, 0xF, 0xF, false));   // quad_perm xor2
    else
        recv = __shfl_xor(send, 1 << LVL, 64);
    return keep + recv;
}

__global__ void __launch_bounds__(256, 4)
scan12(const ushort_t* __restrict__ dt_T,
       ushort_t* uT_ysT,
       const ushort_t* __restrict__ w_T,
       const float2* __restrict__ BCf,
       const float* __restrict__ Alog,
       const float* __restrict__ Dp) {
    __shared__ float2 BCsh[64][64];   // [t][s] fp32 pair; ds_read_b64, 2-way alias
    int tid = threadIdx.x;
    int lane = tid & 63, widx = tid >> 6;
    int wid = blockIdx.x * 4 + widx;
    int b = wid >> 9, d = wid & 511;
    float a2 = -__expf(Alog[d * 64 + lane]) * 1.442695041f;   // log2(e) folded
    float Dd = Dp[d];
    float h = 0.0f;
    size_t rowT = ((size_t)b * 512 + d) * 4096;
    uint_t rowTu = __builtin_amdgcn_readfirstlane((uint_t)rowT);
    size_t base = (size_t)b * LSEQ;
    size_t woff = (size_t)widx * 8192 + (size_t)lane * 16;   // this thread's 16B slot stride base

    // prolog: async direct stage of slab 0 (v10 style), then drain
    {
        const char* gsrc = (const char*)(BCf + ((size_t)base << 6));
        char* ldst = (char*)&BCsh[0][0];
        #pragma unroll
        for (int it = 0; it < 8; ++it)
            gload16(gsrc + woff + (size_t)it * 1024, ldst + woff + (size_t)it * 1024);
    }
    __syncthreads();

    #pragma unroll 1
    for (int sl = 0; sl < 64; ++sl) {
        int t0 = sl * 64;
        // T14: issue next slab's loads into registers (in flight under compute)
        f32x4 pr[8];
        if (sl < 63) {
            const char* gsrc = (const char*)(BCf + (((size_t)(base + t0 + 64)) << 6)) + woff;
            #pragma unroll
            for (int it = 0; it < 8; ++it)
                pr[it] = *(const f32x4*)(gsrc + (size_t)it * 1024);
        }
        const uint_t* dtw = (const uint_t*)(dt_T + rowTu) + (t0 >> 1);
        const uint_t* wwp = (const uint_t*)(w_T + rowTu) + (t0 >> 1);
        float uv = b2f(uT_ysT[rowT + t0 + lane]);
        float acc[4], s4, s5, yfin = 0.0f, v16 = 0.0f;
        #pragma unroll 1
        for (int j1 = 0; j1 < 4; ++j1) {
            #pragma unroll
            for (int jj = 0; jj < 16; ++jj) {
                int j = j1 * 16 + jj;
                uint_t pd = dtw[j >> 1];
                uint_t pw = wwp[j >> 1];
                float sdt = __uint_as_float((jj & 1) ? (pd & 0xFFFF0000u) : (pd << 16));
                float sw  = __uint_as_float((jj & 1) ? (pw & 0xFFFF0000u) : (pw << 16));
                float2 bc = BCsh[j][lane];          // single ds_read_b64
                float dA = __builtin_amdgcn_exp2f(sdt * a2);  // raw v_exp_f32
                float Bw = sw * bc.x;
                h = dA * h + Bw;
                float v = h * bc.y;
                const int dest = (jj == 15) ? 4 : __builtin_ctz(~(unsigned)jj);
                if (0 < dest) v = merge_lvl_t<0>(acc[0], v, lane);
                if (1 < dest) v = merge_lvl_t<1>(acc[1], v, lane);
                if (2 < dest) v = merge_lvl_t<2>(acc[2], v, lane);
                if (3 < dest) v = merge_lvl_t<3>(acc[3], v, lane);
                if (jj == 15) v16 = v;
                else acc[dest] = v;
            }
            if ((j1 & 1) == 0) {
                s4 = v16;
            } else {
                float m = merge_lvl_t<4>(s4, v16, lane);
                if (j1 == 1) s5 = m;
                else yfin = merge_lvl_t<5>(s5, m, lane);
            }
        }
        float y = yfin + uv * Dd;
        uT_ysT[rowT + t0 + lane] = f2b(y);
        __syncthreads();             // all waves done READING BCsh (drains pr loads + y store)
        if (sl < 63) {
            char* ldst = (char*)&BCsh[0][0] + woff;
            #pragma unroll
            for (int it = 0; it < 8; ++it)
                *(f32x4*)(ldst + (size_t)it * 1024) = pr[it];
        }
        __syncthreads();             // LDS refilled for next slab
    }
}

// ---------------- gate + transpose: ys[bt,d] = ysT[b,d,t] * silu(z[bt,d]) ----------------
__global__ void gate_t(const ushort_t* __restrict__ ysT,
                       const ushort_t* __restrict__ zb,
                       ushort_t* __restrict__ ys) {
    int bt0 = blockIdx.x * 64;
    int d0  = blockIdx.y * 64;
    int b   = bt0 >> 12;
    int t0  = bt0 & 4095;
    __shared__ ushort_t tile[64][66];
    int tid = threadIdx.x, lane = tid & 63, widx = tid >> 6;
    for (int dd = widx; dd < 64; dd += 4)
        tile[dd][lane] = ysT[((size_t)b * 512 + d0 + dd) * 4096 + t0 + lane];
    __syncthreads();
    for (int r = widx; r < 64; r += 4) {
        float zv = b2f(zb[((size_t)bt0 + r) * 512 + d0 + lane]);
        float yv = b2f(tile[lane][r]);
        float g = zv / (1.0f + __expf(-zv));
        ys[((size_t)bt0 + r) * 512 + d0 + lane] = f2b(yv * g);
    }
}

// ---------------- final LN + transpose-combine + residual (fp32 out) ----------------
__global__ void final_ln_add(const ushort_t* __restrict__ outm,
                             const float* __restrict__ x,
                             const float* __restrict__ w,
                             const float* __restrict__ bb,
                             float* __restrict__ out) {
    int row = blockIdx.x;
    int c = threadIdx.x;
    int b = row >> 12, l = row & 4095, i = l >> 6, j = l & 63;
    size_t rA = ((size_t)b * LSEQ + l) * DIMC;
    size_t rB = ((size_t)(4 + b) * LSEQ + (j * 64 + i)) * DIMC;
    float va = b2f(outm[rA + c]);
    float vb = b2f(outm[rB + c]);
    float s1 = va, s2 = va * va, s3 = vb, s4 = vb * vb;
    for (int off = 32; off; off >>= 1) {
        s1 += __shfl_xor(s1, off, 64);
        s2 += __shfl_xor(s2, off, 64);
        s3 += __shfl_xor(s3, off, 64);
        s4 += __shfl_xor(s4, off, 64);
    }
    __shared__ float sm[4][4];
    int widx = c >> 6, lane = c & 63;
    if (lane == 0) { sm[widx][0] = s1; sm[widx][1] = s2; sm[widx][2] = s3; sm[widx][3] = s4; }
    __syncthreads();
    s1 = sm[0][0] + sm[1][0] + sm[2][0] + sm[3][0];
    s2 = sm[0][1] + sm[1][1] + sm[2][1] + sm[3][1];
    s3 = sm[0][2] + sm[1][2] + sm[2][2] + sm[3][2];
    s4 = sm[0][3] + sm[1][3] + sm[2][3] + sm[3][3];
    float muA = s1 * (1.0f / 256.0f), varA = s2 * (1.0f / 256.0f) - muA * muA;
    float muB = s3 * (1.0f / 256.0f), varB = s4 * (1.0f / 256.0f) - muB * muB;
    float lw = w[c], lb = bb[c];
    float ya = (va - muA) * rsqrtf(varA + 1e-6f) * lw + lb;
    float yb = (vb - muB) * rsqrtf(varB + 1e-6f) * lw + lb;
    float xo = x[(size_t)row * DIMC + c];
    out[(size_t)row * DIMC + c] = xo + ya + yb;
}

extern "C" void kernel_launch(void* const* d_in, const int* in_sizes, int n_in,
                              void* d_out, int out_size, void* d_ws, size_t ws_size,
                              hipStream_t stream) {
    const float* x      = (const float*)d_in[0];
    const float* ln1_w  = (const float*)d_in[1];
    const float* ln1_b  = (const float*)d_in[2];
    const float* ln2_w  = (const float*)d_in[3];
    const float* ln2_b  = (const float*)d_in[4];
    const float* W_in   = (const float*)d_in[5];
    const float* conv_w = (const float*)d_in[6];
    const float* conv_b = (const float*)d_in[7];
    const float* W_x    = (const float*)d_in[8];
    const float* W_dt   = (const float*)d_in[9];
    const float* b_dt   = (const float*)d_in[10];
    const float* A_log  = (const float*)d_in[11];
    const float* D_par  = (const float*)d_in[12];
    const float* W_out  = (const float*)d_in[13];
    float* out = (float*)d_out;

    // ---- workspace (~169 MB) ----
    char* ws = (char*)d_ws;
    size_t off = 0;
    ushort_t* wb_in  = (ushort_t*)(ws + off); off += (size_t)1024 * 256 * 2;
    ushort_t* wb_x   = (ushort_t*)(ws + off); off += (size_t)144 * 512 * 2;
    ushort_t* wb_out = (ushort_t*)(ws + off); off += (size_t)256 * 512 * 2;
    const size_t R0 = (size_t)MROWS * DIMC * 2;
    const size_t R1 = (size_t)MROWS * 512 * 2;
    ushort_t* r0 = (ushort_t*)(ws + off); off += R0;   // xm -> xdbl -> outm
    ushort_t* r1 = (ushort_t*)(ws + off); off += R1;   // xhalf -> dt_T
    ushort_t* r2 = (ushort_t*)(ws + off); off += R1;   // z
    ushort_t* r3 = (ushort_t*)(ws + off); off += R1;   // xc -> w_T -> ys
    ushort_t* r4 = (ushort_t*)(ws + off); off += R1;   // u_T -> ysT (in place)
    float2*   BCf = (float2*)(ws + off);  off += (size_t)MROWS * 64 * 8;  // 16.8 MB

    ushort_t* xm    = r0;
    ushort_t* xdbl  = r0;
    ushort_t* outm  = r0;
    ushort_t* xhalf = r1;
    ushort_t* dt_T  = r1;
    ushort_t* zb    = r2;
    ushort_t* xc    = r3;
    ushort_t* w_T   = r3;
    ushort_t* ys    = r3;
    ushort_t* u_T   = r4;

    // 0. convert MFMA weights fp32 -> bf16 (one launch)
    const int ncvt = 1024 * 256 + 144 * 512 + 256 * 512;
    hipLaunchKernelGGL(cvtw3, dim3((ncvt + 255) / 256), dim3(256), 0, stream,
                       W_in, wb_in, W_x, wb_x, W_out, wb_out);

    // A. LayerNorm + dual-order xm
    hipLaunchKernelGGL(ln1_build_xm, dim3(4 * LSEQ), dim3(256), 0, stream,
                       x, ln1_w, ln1_b, xm);
    // B. one launch: cols<512 -> xhalf, cols>=512 -> zb
    hipLaunchKernelGGL(gemm128_split, dim3(MROWS / 128, 8), dim3(256), 0, stream,
                       xm, wb_in, xhalf, zb);
    // C. tiled conv + SiLU: xhalf -> xc[bt,d] + u_T[b,d,t]
    hipLaunchKernelGGL(conv_silu_t, dim3(MROWS / 64, 8), dim3(256), 0, stream,
                       xhalf, conv_w, conv_b, xc, u_T);
    // D. x_dbl = xc @ W_x^T   (N=144, K=512)
    hipLaunchKernelGGL(gemm128, dim3(MROWS / 128, 2), dim3(256), 0, stream,
                       xc, wb_x, xdbl, MROWS, 144, 512);
    // E. dt_T = softplus(...), w_T = dt*u, + fused B/C fp32 unpack
    hipLaunchKernelGGL(dt_sp_t, dim3(MROWS / 64, 8), dim3(256), 0, stream,
                       xdbl, W_dt, b_dt, u_T, dt_T, w_T, BCf);
    // F. selective scan v12: u_T -> ysT in place
    hipLaunchKernelGGL(scan12, dim3(BS2 * 512 / 4), dim3(256), 0, stream,
                       dt_T, u_T, w_T, BCf, A_log, D_par);
    // G. gate + transpose: ys[bt,d] = ysT * silu(z)
    hipLaunchKernelGGL(gate_t, dim3(MROWS / 64, 8), dim3(256), 0, stream,
                       u_T, zb, ys);
    // H. outm = ys @ W_out^T   (N=256, K=512)
    hipLaunchKernelGGL(gemm128, dim3(MROWS / 128, 2), dim3(256), 0, stream,
                       ys, wb_out, outm, MROWS, 256, 512);
    // I. final LN + transpose combine + residual (fp32 out)
    hipLaunchKernelGGL(final_ln_add, dim3(4 * LSEQ), dim3(256), 0, stream,
                       outm, x, ln2_w, ln2_b, out);
}

// Round 3
// 711.057 us; speedup vs baseline: 1.1949x; 1.0208x over previous
//
#include <hip/hip_runtime.h>
#include <hip/hip_bf16.h>

typedef unsigned short ushort_t;
typedef unsigned int uint_t;
typedef __attribute__((ext_vector_type(8))) short short8;
typedef __attribute__((ext_vector_type(4))) float f32x4;

#define DIMC 256
#define D_INNER 512
#define D_STATE 64
#define DT_RANK 16
#define LSEQ 4096
#define BS2 8            // 2*BS batches through mamba
#define MROWS (BS2*LSEQ) // 32768

__device__ __forceinline__ float b2f(ushort_t u) {
    union { uint_t i; float f; } v; v.i = ((uint_t)u) << 16; return v.f;
}
__device__ __forceinline__ ushort_t f2b(float f) {
    union { float f; uint_t i; } v; v.f = f;
    uint_t r = v.i + 0x7FFFu + ((v.i >> 16) & 1u);   // RNE
    return (ushort_t)(r >> 16);
}

// async global->LDS 16B per lane (HW: wave-uniform LDS base + lane*16)
typedef __attribute__((address_space(1))) const unsigned int gas_u32;
typedef __attribute__((address_space(3))) unsigned int las_u32;
__device__ __forceinline__ void gload16(const void* g, void* l) {
    __builtin_amdgcn_global_load_lds((gas_u32*)g, (las_u32*)l, 16, 0, 0);
}

// ---------------- fp32 -> bf16 conversion of the 3 MFMA weight mats ----------------
__global__ void cvtw3(const float* __restrict__ s0, ushort_t* __restrict__ d0,
                      const float* __restrict__ s1, ushort_t* __restrict__ d1,
                      const float* __restrict__ s2, ushort_t* __restrict__ d2) {
    int i = blockIdx.x * 256 + threadIdx.x;
    const int n0 = 1024 * 256, n1 = 144 * 512, n2 = 256 * 512;
    if (i < n0) d0[i] = f2b(s0[i]);
    else if (i < n0 + n1) d1[i - n0] = f2b(s1[i - n0]);
    else if (i < n0 + n1 + n2) d2[i - n0 - n1] = f2b(s2[i - n0 - n1]);
}

// ---------------- LN1 + build xm (both orders), fp32 in, bf16 out ----------------
__global__ void ln1_build_xm(const float* __restrict__ x,
                             const float* __restrict__ w,
                             const float* __restrict__ bb,
                             ushort_t* __restrict__ xm) {
    int row = blockIdx.x;            // b*4096 + l  (b in 0..3)
    int c = threadIdx.x;             // 0..255
    float v = x[(size_t)row * DIMC + c];
    float s1 = v, s2 = v * v;
    for (int off = 32; off; off >>= 1) {
        s1 += __shfl_xor(s1, off, 64);
        s2 += __shfl_xor(s2, off, 64);
    }
    __shared__ float sa[4], sb[4];
    int widx = c >> 6, lane = c & 63;
    if (lane == 0) { sa[widx] = s1; sb[widx] = s2; }
    __syncthreads();
    s1 = sa[0] + sa[1] + sa[2] + sa[3];
    s2 = sb[0] + sb[1] + sb[2] + sb[3];
    float mu = s1 * (1.0f / 256.0f);
    float var = s2 * (1.0f / 256.0f) - mu * mu;
    float xn = (v - mu) * rsqrtf(var + 1e-6f) * w[c] + bb[c];
    ushort_t o = f2b(xn);
    int b = row >> 12, l = row & 4095, i = l >> 6, j = l & 63;
    xm[((size_t)b * LSEQ + l) * DIMC + c] = o;
    xm[((size_t)(4 + b) * LSEQ + (j * 64 + i)) * DIMC + c] = o;
}

// ---------------- 128x128 LDS-tiled NT GEMM with global_load_lds staging ----------------
__global__ void __launch_bounds__(256, 4)
gemm128(const ushort_t* __restrict__ A,
        const ushort_t* __restrict__ W,
        ushort_t* __restrict__ C, int M, int N, int K) {
    __shared__ ushort_t Ash[128 * 32];
    __shared__ ushort_t Bsh[128 * 32];
    int tid = threadIdx.x;
    int lane = tid & 63, widx = tid >> 6;
    int wm = widx & 1, wn = widx >> 1;
    int l16 = lane & 15, quad = lane >> 4;
    int mblk = blockIdx.x * 128, nblk = blockIdx.y * 128;
    f32x4 acc[4][4];
    #pragma unroll
    for (int i = 0; i < 4; ++i)
        #pragma unroll
        for (int j = 0; j < 4; ++j)
            acc[i][j] = f32x4{0.0f, 0.0f, 0.0f, 0.0f};
    int srow = tid >> 2;
    int sseg = (tid & 3) * 8;
    bool jv[4];
    #pragma unroll
    for (int j = 0; j < 4; ++j) jv[j] = (nblk + wn * 64 + j * 16) < N;

    for (int k0 = 0; k0 < K; k0 += 32) {
        __syncthreads();
        #pragma unroll
        for (int q = 0; q < 2; ++q) {
            int row = q * 64 + srow;
            gload16(&A[(size_t)(mblk + row) * K + k0 + sseg], &Ash[row * 32 + sseg]);
            gload16(&W[(size_t)(nblk + row) * K + k0 + sseg], &Bsh[row * 32 + sseg]);
        }
        __syncthreads();
        short8 af[4], bf[4];
        #pragma unroll
        for (int i = 0; i < 4; ++i)
            af[i] = *(const short8*)&Ash[(wm * 64 + i * 16 + l16) * 32 + quad * 8];
        #pragma unroll
        for (int j = 0; j < 4; ++j)
            bf[j] = *(const short8*)&Bsh[(wn * 64 + j * 16 + l16) * 32 + quad * 8];
        #pragma unroll
        for (int i = 0; i < 4; ++i)
            #pragma unroll
            for (int j = 0; j < 4; ++j)
                if (jv[j])
                    acc[i][j] = __builtin_amdgcn_mfma_f32_16x16x32_bf16(af[i], bf[j], acc[i][j], 0, 0, 0);
    }
    #pragma unroll
    for (int i = 0; i < 4; ++i) {
        #pragma unroll
        for (int j = 0; j < 4; ++j) {
            if (!jv[j]) continue;
            int col = nblk + wn * 64 + j * 16 + l16;
            #pragma unroll
            for (int r = 0; r < 4; ++r) {
                int row = mblk + wm * 64 + i * 16 + quad * 4 + r;
                C[(size_t)row * N + col] = f2b(acc[i][j][r]);
            }
        }
    }
}

// ---------------- gemm128 variant: K=256, N=1024, split outputs at col 512 ----------------
__global__ void __launch_bounds__(256, 4)
gemm128_split(const ushort_t* __restrict__ A,
              const ushort_t* __restrict__ W,
              ushort_t* __restrict__ outX,   // cols 0..511
              ushort_t* __restrict__ outZ) { // cols 512..1023
    const int K = 256;
    __shared__ ushort_t Ash[128 * 32];
    __shared__ ushort_t Bsh[128 * 32];
    int tid = threadIdx.x;
    int lane = tid & 63, widx = tid >> 6;
    int wm = widx & 1, wn = widx >> 1;
    int l16 = lane & 15, quad = lane >> 4;
    int mblk = blockIdx.x * 128, nblk = blockIdx.y * 128;
    f32x4 acc[4][4];
    #pragma unroll
    for (int i = 0; i < 4; ++i)
        #pragma unroll
        for (int j = 0; j < 4; ++j)
            acc[i][j] = f32x4{0.0f, 0.0f, 0.0f, 0.0f};
    int srow = tid >> 2;
    int sseg = (tid & 3) * 8;
    for (int k0 = 0; k0 < K; k0 += 32) {
        __syncthreads();
        #pragma unroll
        for (int q = 0; q < 2; ++q) {
            int row = q * 64 + srow;
            gload16(&A[(size_t)(mblk + row) * K + k0 + sseg], &Ash[row * 32 + sseg]);
            gload16(&W[(size_t)(nblk + row) * K + k0 + sseg], &Bsh[row * 32 + sseg]);
        }
        __syncthreads();
        short8 af[4], bf[4];
        #pragma unroll
        for (int i = 0; i < 4; ++i)
            af[i] = *(const short8*)&Ash[(wm * 64 + i * 16 + l16) * 32 + quad * 8];
        #pragma unroll
        for (int j = 0; j < 4; ++j)
            bf[j] = *(const short8*)&Bsh[(wn * 64 + j * 16 + l16) * 32 + quad * 8];
        #pragma unroll
        for (int i = 0; i < 4; ++i)
            #pragma unroll
            for (int j = 0; j < 4; ++j)
                acc[i][j] = __builtin_amdgcn_mfma_f32_16x16x32_bf16(af[i], bf[j], acc[i][j], 0, 0, 0);
    }
    #pragma unroll
    for (int i = 0; i < 4; ++i) {
        #pragma unroll
        for (int j = 0; j < 4; ++j) {
            int colg = nblk + wn * 64 + j * 16 + l16;    // tile never straddles 512
            ushort_t* dst = (colg < 512) ? outX : outZ;
            int col = colg & 511;
            #pragma unroll
            for (int r = 0; r < 4; ++r) {
                int row = mblk + wm * 64 + i * 16 + quad * 4 + r;
                dst[(size_t)row * 512 + col] = f2b(acc[i][j][r]);
            }
        }
    }
}

// ---------------- tiled conv(4)+SiLU: all-coalesced, dual output ----------------
__global__ void conv_silu_t(const ushort_t* __restrict__ xh,
                            const float* __restrict__ cw,
                            const float* __restrict__ cb,
                            ushort_t* __restrict__ xc,
                            ushort_t* __restrict__ u_T) {
    int bt0 = blockIdx.x * 64;
    int d0  = blockIdx.y * 64;
    int b   = bt0 >> 12;
    int t0  = bt0 & 4095;
    __shared__ ushort_t tin[67][66];
    __shared__ ushort_t tout[64][66];
    int tid = threadIdx.x, lane = tid & 63, widx = tid >> 6;
    for (int r = widx; r < 67; r += 4) {
        int tt = t0 - 3 + r;
        tin[r][lane] = (tt >= 0) ? xh[((size_t)bt0 - 3 + r) * 512 + d0 + lane] : (ushort_t)0;
    }
    __syncthreads();
    for (int dd = widx; dd < 64; dd += 4) {
        int d = d0 + dd;
        float acc = cb[d];
        #pragma unroll
        for (int k = 0; k < 4; ++k)
            acc += cw[d * 4 + k] * b2f(tin[lane + k][dd]);
        float s = acc / (1.0f + __expf(-acc));
        ushort_t o = f2b(s);
        u_T[((size_t)b * 512 + d) * 4096 + t0 + lane] = o;
        tout[lane][dd] = o;
    }
    __syncthreads();
    for (int r = widx; r < 64; r += 4)
        xc[((size_t)bt0 + r) * 512 + d0 + lane] = tout[r][lane];
}

// ---------------- tiled dt/w (+fused B/C pair-interleaved unpack) ----------------
// F32DW: dt/w written as fp32 pairs (dt, dt*u) -> dwf; else bf16 dt_T/w_T (fallback).
// BCfI layout: [pair=bt/2][s][2] as f32x4 (B_e,C_e,B_o,C_o) -> scan reads b128/2steps.
template<bool F32DW>
__global__ void dt_sp_t(const ushort_t* __restrict__ xdbl,
                        const float* __restrict__ wdt,
                        const float* __restrict__ bdt,
                        const ushort_t* __restrict__ u_T,
                        ushort_t* __restrict__ dt_T,
                        ushort_t* __restrict__ w_T,
                        float2* __restrict__ dwf,
                        f32x4* __restrict__ BCfI) {
    int bt0 = blockIdx.x * 64;
    int d0  = blockIdx.y * 64;
    int b   = bt0 >> 12;
    int t0  = bt0 & 4095;
    __shared__ float din[64][17];
    int tid = threadIdx.x;
    for (int i = tid; i < 64 * 16; i += 256) {
        int r = i >> 4, k = i & 15;
        din[r][k] = b2f(xdbl[((size_t)bt0 + r) * 144 + k]);
    }
    __syncthreads();
    int lane = tid & 63, widx = tid >> 6;
    for (int dd = widx; dd < 64; dd += 4) {
        int d = d0 + dd;
        float acc = bdt[d];
        #pragma unroll
        for (int k = 0; k < 16; ++k)
            acc += din[lane][k] * wdt[d * 16 + k];
        float sp = (acc > 20.0f) ? acc : log1pf(__expf(acc));
        size_t idx = ((size_t)b * 512 + d) * 4096 + t0 + lane;
        float uvv = b2f(u_T[idx]);
        if constexpr (F32DW) {
            dwf[idx] = make_float2(sp, sp * uvv);
        } else {
            dt_T[idx] = f2b(sp);
            w_T[idx] = f2b(sp * uvv);
        }
    }
    // fused B/C unpack, pair-interleaved (one d-slice of blocks covers it)
    if (blockIdx.y == 0) {
        for (int i = tid; i < 32 * 64; i += 256) {
            int p = i >> 6, s = i & 63;
            const ushort_t* rpe = xdbl + ((size_t)bt0 + 2 * p) * 144;
            const ushort_t* rpo = rpe + 144;
            f32x4 v;
            v.x = b2f(rpe[16 + s]); v.y = b2f(rpe[80 + s]);
            v.z = b2f(rpo[16 + s]); v.w = b2f(rpo[80 + s]);
            BCfI[((size_t)(bt0 >> 1) + p) * 64 + s] = v;
        }
    }
}

// ---------------- selective scan v13 ----------------
// vs v12: (1) sched_barrier(0) pins the T14 prefetch issue (v12's loads were
// legally sunk past the barrier — VGPR_Count stayed 44); (2) fp32 (dt, dt*u)
// pairs, one dwordx4 per 2 steps, no bf16 unpacks; (3) BCf pair-interleaved ->
// ds_read_b128 per 2 steps; (4) lvl4/5 merges via v_permlane16/32_swap
// (correctness HW-verified in v11).
template<int LVL>
__device__ __forceinline__ float merge_lvl_t(float left, float right, int lane) {
    bool bit = (lane >> LVL) & 1;
    float send = bit ? left : right;
    float keep = bit ? right : left;
    float recv;
    if constexpr (LVL == 0)
        recv = __int_as_float(__builtin_amdgcn_update_dpp(
            0, __float_as_int(send), 0xB1, 0xF, 0xF, false));   // quad_perm xor1
    else if constexpr (LVL == 1)
        recv = __int_as_float(__builtin_amdgcn_update_dpp(
            0, __float_as_int(send), 0x4E, 0xF, 0xF, false));   // quad_perm xor2
    else
        recv = __shfl_xor(send, 1 << LVL, 64);
    return keep + recv;
}
// lvl4: rows16: [L0+L1, R0+R1, L2+L3, R2+R3] == old merge<4> placement (HW-verified v11)
__device__ __forceinline__ float merge16_swap(float a, float b) {
    asm volatile("s_nop 1\n\tv_permlane16_swap_b32 %0, %1" : "+v"(a), "+v"(b));
    return a + b;
}
// lvl5: [L.h0+L.h1, R.h0+R.h1] == old merge<5> placement (HW-verified v11)
__device__ __forceinline__ float merge32_swap(float a, float b) {
    asm volatile("s_nop 1\n\tv_permlane32_swap_b32 %0, %1" : "+v"(a), "+v"(b));
    return a + b;
}

template<bool F32DW>
__global__ void __launch_bounds__(256, 4)
scan13(const ushort_t* __restrict__ dt_T,
       ushort_t* uT_ysT,
       const ushort_t* __restrict__ w_T,
       const float2* __restrict__ dwf,
       const f32x4* __restrict__ BCfI,
       const float* __restrict__ Alog,
       const float* __restrict__ Dp) {
    __shared__ f32x4 BCsh[32][64];   // [pair][s]: (B_e, C_e, B_o, C_o)
    int tid = threadIdx.x;
    int lane = tid & 63, widx = tid >> 6;
    int wid = blockIdx.x * 4 + widx;
    int b = wid >> 9, d = wid & 511;
    float a2 = -__expf(Alog[d * 64 + lane]) * 1.442695041f;   // log2(e) folded
    float Dd = Dp[d];
    float h = 0.0f;
    size_t rowT = ((size_t)b * 512 + d) * 4096;
    uint_t rowTu = __builtin_amdgcn_readfirstlane((uint_t)rowT);
    size_t base = (size_t)b * LSEQ;
    size_t woff = (size_t)widx * 8192 + (size_t)lane * 16;
    const f32x4* dwrow = (const f32x4*)dwf + (rowTu >> 1);

    // prolog: async direct stage of slab 0, then drain
    {
        const char* gsrc = (const char*)BCfI + base * 512;
        char* ldst = (char*)&BCsh[0][0];
        #pragma unroll
        for (int it = 0; it < 8; ++it)
            gload16(gsrc + woff + (size_t)it * 1024, ldst + woff + (size_t)it * 1024);
    }
    __syncthreads();

    #pragma unroll 1
    for (int sl = 0; sl < 64; ++sl) {
        int t0 = sl * 64;
        // T14: issue next slab's loads into registers, PINNED early by sched_barrier
        f32x4 pr[8];
        if (sl < 63) {
            const char* gsrc = (const char*)BCfI + (size_t)(base + t0 + 64) * 512 + woff;
            #pragma unroll
            for (int it = 0; it < 8; ++it)
                pr[it] = *(const f32x4*)(gsrc + (size_t)it * 1024);
        }
        __builtin_amdgcn_sched_barrier(0);   // loads cannot sink below this point
        const uint_t* dtw; const uint_t* wwp; const f32x4* dw4;
        if constexpr (F32DW) {
            dw4 = dwrow + (t0 >> 1);
        } else {
            dtw = (const uint_t*)(dt_T + rowTu) + (t0 >> 1);
            wwp = (const uint_t*)(w_T + rowTu) + (t0 >> 1);
        }
        float uv = b2f(uT_ysT[rowT + t0 + lane]);
        float acc[4], s4, s5, yfin = 0.0f, v16 = 0.0f;
        f32x4 qd, qb;
        #pragma unroll 1
        for (int j1 = 0; j1 < 4; ++j1) {
            #pragma unroll
            for (int jj = 0; jj < 16; ++jj) {
                int j = j1 * 16 + jj;
                float sdt, sw;
                if constexpr (F32DW) {
                    if ((jj & 1) == 0) qd = dw4[j >> 1];
                    sdt = (jj & 1) ? qd.z : qd.x;
                    sw  = (jj & 1) ? qd.w : qd.y;
                } else {
                    uint_t pd = dtw[j >> 1];
                    uint_t pw = wwp[j >> 1];
                    sdt = __uint_as_float((jj & 1) ? (pd & 0xFFFF0000u) : (pd << 16));
                    sw  = __uint_as_float((jj & 1) ? (pw & 0xFFFF0000u) : (pw << 16));
                }
                if ((jj & 1) == 0) qb = BCsh[j >> 1][lane];    // ds_read_b128 / 2 steps
                float bcx = (jj & 1) ? qb.z : qb.x;
                float bcy = (jj & 1) ? qb.w : qb.y;
                float dA = __builtin_amdgcn_exp2f(sdt * a2);   // raw v_exp_f32
                h = dA * h + sw * bcx;
                float v = h * bcy;
                const int dest = (jj == 15) ? 4 : __builtin_ctz(~(unsigned)jj);
                if (0 < dest) v = merge_lvl_t<0>(acc[0], v, lane);
                if (1 < dest) v = merge_lvl_t<1>(acc[1], v, lane);
                if (2 < dest) v = merge_lvl_t<2>(acc[2], v, lane);
                if (3 < dest) v = merge_lvl_t<3>(acc[3], v, lane);
                if (jj == 15) v16 = v;
                else acc[dest] = v;
            }
            if ((j1 & 1) == 0) {
                s4 = v16;
            } else {
                float m = merge16_swap(s4, v16);
                if (j1 == 1) s5 = m;
                else yfin = merge32_swap(s5, m);
            }
        }
        float y = yfin + uv * Dd;
        uT_ysT[rowT + t0 + lane] = f2b(y);
        __syncthreads();             // all waves done READING BCsh
        if (sl < 63) {
            char* ldst = (char*)&BCsh[0][0] + woff;
            #pragma unroll
            for (int it = 0; it < 8; ++it)
                *(f32x4*)(ldst + (size_t)it * 1024) = pr[it];
        }
        __syncthreads();             // LDS refilled for next slab
    }
}

// ---------------- gate + transpose: ys[bt,d] = ysT[b,d,t] * silu(z[bt,d]) ----------------
__global__ void gate_t(const ushort_t* __restrict__ ysT,
                       const ushort_t* __restrict__ zb,
                       ushort_t* __restrict__ ys) {
    int bt0 = blockIdx.x * 64;
    int d0  = blockIdx.y * 64;
    int b   = bt0 >> 12;
    int t0  = bt0 & 4095;
    __shared__ ushort_t tile[64][66];
    int tid = threadIdx.x, lane = tid & 63, widx = tid >> 6;
    for (int dd = widx; dd < 64; dd += 4)
        tile[dd][lane] = ysT[((size_t)b * 512 + d0 + dd) * 4096 + t0 + lane];
    __syncthreads();
    for (int r = widx; r < 64; r += 4) {
        float zv = b2f(zb[((size_t)bt0 + r) * 512 + d0 + lane]);
        float yv = b2f(tile[lane][r]);
        float g = zv / (1.0f + __expf(-zv));
        ys[((size_t)bt0 + r) * 512 + d0 + lane] = f2b(yv * g);
    }
}

// ---------------- final LN + transpose-combine + residual (fp32 out) ----------------
__global__ void final_ln_add(const ushort_t* __restrict__ outm,
                             const float* __restrict__ x,
                             const float* __restrict__ w,
                             const float* __restrict__ bb,
                             float* __restrict__ out) {
    int row = blockIdx.x;
    int c = threadIdx.x;
    int b = row >> 12, l = row & 4095, i = l >> 6, j = l & 63;
    size_t rA = ((size_t)b * LSEQ + l) * DIMC;
    size_t rB = ((size_t)(4 + b) * LSEQ + (j * 64 + i)) * DIMC;
    float va = b2f(outm[rA + c]);
    float vb = b2f(outm[rB + c]);
    float s1 = va, s2 = va * va, s3 = vb, s4 = vb * vb;
    for (int off = 32; off; off >>= 1) {
        s1 += __shfl_xor(s1, off, 64);
        s2 += __shfl_xor(s2, off, 64);
        s3 += __shfl_xor(s3, off, 64);
        s4 += __shfl_xor(s4, off, 64);
    }
    __shared__ float sm[4][4];
    int widx = c >> 6, lane = c & 63;
    if (lane == 0) { sm[widx][0] = s1; sm[widx][1] = s2; sm[widx][2] = s3; sm[widx][3] = s4; }
    __syncthreads();
    s1 = sm[0][0] + sm[1][0] + sm[2][0] + sm[3][0];
    s2 = sm[0][1] + sm[1][1] + sm[2][1] + sm[3][1];
    s3 = sm[0][2] + sm[1][2] + sm[2][2] + sm[3][2];
    s4 = sm[0][3] + sm[1][3] + sm[2][3] + sm[3][3];
    float muA = s1 * (1.0f / 256.0f), varA = s2 * (1.0f / 256.0f) - muA * muA;
    float muB = s3 * (1.0f / 256.0f), varB = s4 * (1.0f / 256.0f) - muB * muB;
    float lw = w[c], lb = bb[c];
    float ya = (va - muA) * rsqrtf(varA + 1e-6f) * lw + lb;
    float yb = (vb - muB) * rsqrtf(varB + 1e-6f) * lw + lb;
    float xo = x[(size_t)row * DIMC + c];
    out[(size_t)row * DIMC + c] = xo + ya + yb;
}

extern "C" void kernel_launch(void* const* d_in, const int* in_sizes, int n_in,
                              void* d_out, int out_size, void* d_ws, size_t ws_size,
                              hipStream_t stream) {
    const float* x      = (const float*)d_in[0];
    const float* ln1_w  = (const float*)d_in[1];
    const float* ln1_b  = (const float*)d_in[2];
    const float* ln2_w  = (const float*)d_in[3];
    const float* ln2_b  = (const float*)d_in[4];
    const float* W_in   = (const float*)d_in[5];
    const float* conv_w = (const float*)d_in[6];
    const float* conv_b = (const float*)d_in[7];
    const float* W_x    = (const float*)d_in[8];
    const float* W_dt   = (const float*)d_in[9];
    const float* b_dt   = (const float*)d_in[10];
    const float* A_log  = (const float*)d_in[11];
    const float* D_par  = (const float*)d_in[12];
    const float* W_out  = (const float*)d_in[13];
    float* out = (float*)d_out;

    // ---- workspace ----
    char* ws = (char*)d_ws;
    size_t off = 0;
    ushort_t* wb_in  = (ushort_t*)(ws + off); off += (size_t)1024 * 256 * 2;
    ushort_t* wb_x   = (ushort_t*)(ws + off); off += (size_t)144 * 512 * 2;
    ushort_t* wb_out = (ushort_t*)(ws + off); off += (size_t)256 * 512 * 2;
    const size_t R0 = (size_t)MROWS * DIMC * 2;
    const size_t R1 = (size_t)MROWS * 512 * 2;
    ushort_t* r0 = (ushort_t*)(ws + off); off += R0;   // xm -> xdbl -> outm
    ushort_t* r1 = (ushort_t*)(ws + off); off += R1;   // xhalf -> dt_T
    ushort_t* r2 = (ushort_t*)(ws + off); off += R1;   // z
    ushort_t* r3 = (ushort_t*)(ws + off); off += R1;   // xc -> w_T -> ys
    ushort_t* r4 = (ushort_t*)(ws + off); off += R1;   // u_T -> ysT (in place)
    f32x4*    BCfI = (f32x4*)(ws + off);  off += (size_t)MROWS * 64 * 8;  // 16.8 MB
    float2*   dwf  = (float2*)(ws + off);
    size_t need_f32 = off + (size_t)MROWS * 512 * 8;   // +134 MB fp32 (dt, dt*u)
    bool f32dw = (ws_size >= need_f32);

    ushort_t* xm    = r0;
    ushort_t* xdbl  = r0;
    ushort_t* outm  = r0;
    ushort_t* xhalf = r1;
    ushort_t* dt_T  = r1;
    ushort_t* zb    = r2;
    ushort_t* xc    = r3;
    ushort_t* w_T   = r3;
    ushort_t* ys    = r3;
    ushort_t* u_T   = r4;

    // 0. convert MFMA weights fp32 -> bf16 (one launch)
    const int ncvt = 1024 * 256 + 144 * 512 + 256 * 512;
    hipLaunchKernelGGL(cvtw3, dim3((ncvt + 255) / 256), dim3(256), 0, stream,
                       W_in, wb_in, W_x, wb_x, W_out, wb_out);

    // A. LayerNorm + dual-order xm
    hipLaunchKernelGGL(ln1_build_xm, dim3(4 * LSEQ), dim3(256), 0, stream,
                       x, ln1_w, ln1_b, xm);
    // B. one launch: cols<512 -> xhalf, cols>=512 -> zb
    hipLaunchKernelGGL(gemm128_split, dim3(MROWS / 128, 8), dim3(256), 0, stream,
                       xm, wb_in, xhalf, zb);
    // C. tiled conv + SiLU: xhalf -> xc[bt,d] + u_T[b,d,t]
    hipLaunchKernelGGL(conv_silu_t, dim3(MROWS / 64, 8), dim3(256), 0, stream,
                       xhalf, conv_w, conv_b, xc, u_T);
    // D. x_dbl = xc @ W_x^T   (N=144, K=512)
    hipLaunchKernelGGL(gemm128, dim3(MROWS / 128, 2), dim3(256), 0, stream,
                       xc, wb_x, xdbl, MROWS, 144, 512);
    // E. dt/w (+ pair-interleaved B/C unpack)
    if (f32dw)
        hipLaunchKernelGGL((dt_sp_t<true>), dim3(MROWS / 64, 8), dim3(256), 0, stream,
                           xdbl, W_dt, b_dt, u_T, dt_T, w_T, dwf, BCfI);
    else
        hipLaunchKernelGGL((dt_sp_t<false>), dim3(MROWS / 64, 8), dim3(256), 0, stream,
                           xdbl, W_dt, b_dt, u_T, dt_T, w_T, dwf, BCfI);
    // F. selective scan v13: u_T -> ysT in place
    if (f32dw)
        hipLaunchKernelGGL((scan13<true>), dim3(BS2 * 512 / 4), dim3(256), 0, stream,
                           dt_T, u_T, w_T, dwf, BCfI, A_log, D_par);
    else
        hipLaunchKernelGGL((scan13<false>), dim3(BS2 * 512 / 4), dim3(256), 0, stream,
                           dt_T, u_T, w_T, dwf, BCfI, A_log, D_par);
    // G. gate + transpose: ys[bt,d] = ysT * silu(z)
    hipLaunchKernelGGL(gate_t, dim3(MROWS / 64, 8), dim3(256), 0, stream,
                       u_T, zb, ys);
    // H. outm = ys @ W_out^T   (N=256, K=512)
    hipLaunchKernelGGL(gemm128, dim3(MROWS / 128, 2), dim3(256), 0, stream,
                       ys, wb_out, outm, MROWS, 256, 512);
    // I. final LN + transpose combine + residual (fp32 out)
    hipLaunchKernelGGL(final_ln_add, dim3(4 * LSEQ), dim3(256), 0, stream,
                       outm, x, ln2_w, ln2_b, out);
}

// Round 5
// 706.817 us; speedup vs baseline: 1.2021x; 1.0060x over previous
//
#include <hip/hip_runtime.h>
#include <hip/hip_bf16.h>

typedef unsigned short ushort_t;
typedef unsigned int uint_t;
typedef __attribute__((ext_vector_type(8))) short short8;
typedef __attribute__((ext_vector_type(4))) float f32x4;

#define DIMC 256
#define D_INNER 512
#define D_STATE 64
#define DT_RANK 16
#define LSEQ 4096
#define BS2 8            // 2*BS batches through mamba
#define MROWS (BS2*LSEQ) // 32768

// lane-bit permutation for the scan merge tree:
// t-bit b -> lane-xor bit pi(b): pi = {0,1,3,4,5,2}
// Pinv(p): t = (p&3) | ((p&0x38)>>1) | ((p&4)<<3)
__device__ __forceinline__ int perm_inv(int p) {
    return (p & 3) | ((p & 0x38) >> 1) | ((p & 4) << 3);
}

__device__ __forceinline__ float b2f(ushort_t u) {
    union { uint_t i; float f; } v; v.i = ((uint_t)u) << 16; return v.f;
}
__device__ __forceinline__ ushort_t f2b(float f) {
    union { float f; uint_t i; } v; v.f = f;
    uint_t r = v.i + 0x7FFFu + ((v.i >> 16) & 1u);   // RNE
    return (ushort_t)(r >> 16);
}

// async global->LDS 16B per lane (HW: wave-uniform LDS base + lane*16)
typedef __attribute__((address_space(1))) const unsigned int gas_u32;
typedef __attribute__((address_space(3))) unsigned int las_u32;
__device__ __forceinline__ void gload16(const void* g, void* l) {
    __builtin_amdgcn_global_load_lds((gas_u32*)g, (las_u32*)l, 16, 0, 0);
}

// ---------------- fp32 -> bf16 conversion of the 3 MFMA weight mats ----------------
__global__ void cvtw3(const float* __restrict__ s0, ushort_t* __restrict__ d0,
                      const float* __restrict__ s1, ushort_t* __restrict__ d1,
                      const float* __restrict__ s2, ushort_t* __restrict__ d2) {
    int i = blockIdx.x * 256 + threadIdx.x;
    const int n0 = 1024 * 256, n1 = 144 * 512, n2 = 256 * 512;
    if (i < n0) d0[i] = f2b(s0[i]);
    else if (i < n0 + n1) d1[i - n0] = f2b(s1[i - n0]);
    else if (i < n0 + n1 + n2) d2[i - n0 - n1] = f2b(s2[i - n0 - n1]);
}

// ---------------- LN1 + build xm (both orders), fp32 in, bf16 out ----------------
__global__ void ln1_build_xm(const float* __restrict__ x,
                             const float* __restrict__ w,
                             const float* __restrict__ bb,
                             ushort_t* __restrict__ xm) {
    int row = blockIdx.x;            // b*4096 + l  (b in 0..3)
    int c = threadIdx.x;             // 0..255
    float v = x[(size_t)row * DIMC + c];
    float s1 = v, s2 = v * v;
    for (int off = 32; off; off >>= 1) {
        s1 += __shfl_xor(s1, off, 64);
        s2 += __shfl_xor(s2, off, 64);
    }
    __shared__ float sa[4], sb[4];
    int widx = c >> 6, lane = c & 63;
    if (lane == 0) { sa[widx] = s1; sb[widx] = s2; }
    __syncthreads();
    s1 = sa[0] + sa[1] + sa[2] + sa[3];
    s2 = sb[0] + sb[1] + sb[2] + sb[3];
    float mu = s1 * (1.0f / 256.0f);
    float var = s2 * (1.0f / 256.0f) - mu * mu;
    float xn = (v - mu) * rsqrtf(var + 1e-6f) * w[c] + bb[c];
    ushort_t o = f2b(xn);
    int b = row >> 12, l = row & 4095, i = l >> 6, j = l & 63;
    xm[((size_t)b * LSEQ + l) * DIMC + c] = o;
    xm[((size_t)(4 + b) * LSEQ + (j * 64 + i)) * DIMC + c] = o;
}

// ---------------- 128x128 LDS-tiled NT GEMM with global_load_lds staging ----------------
__global__ void __launch_bounds__(256, 4)
gemm128(const ushort_t* __restrict__ A,
        const ushort_t* __restrict__ W,
        ushort_t* __restrict__ C, int M, int N, int K) {
    __shared__ ushort_t Ash[128 * 32];
    __shared__ ushort_t Bsh[128 * 32];
    int tid = threadIdx.x;
    int lane = tid & 63, widx = tid >> 6;
    int wm = widx & 1, wn = widx >> 1;
    int l16 = lane & 15, quad = lane >> 4;
    int mblk = blockIdx.x * 128, nblk = blockIdx.y * 128;
    f32x4 acc[4][4];
    #pragma unroll
    for (int i = 0; i < 4; ++i)
        #pragma unroll
        for (int j = 0; j < 4; ++j)
            acc[i][j] = f32x4{0.0f, 0.0f, 0.0f, 0.0f};
    int srow = tid >> 2;
    int sseg = (tid & 3) * 8;
    bool jv[4];
    #pragma unroll
    for (int j = 0; j < 4; ++j) jv[j] = (nblk + wn * 64 + j * 16) < N;

    for (int k0 = 0; k0 < K; k0 += 32) {
        __syncthreads();
        #pragma unroll
        for (int q = 0; q < 2; ++q) {
            int row = q * 64 + srow;
            gload16(&A[(size_t)(mblk + row) * K + k0 + sseg], &Ash[row * 32 + sseg]);
            gload16(&W[(size_t)(nblk + row) * K + k0 + sseg], &Bsh[row * 32 + sseg]);
        }
        __syncthreads();
        short8 af[4], bf[4];
        #pragma unroll
        for (int i = 0; i < 4; ++i)
            af[i] = *(const short8*)&Ash[(wm * 64 + i * 16 + l16) * 32 + quad * 8];
        #pragma unroll
        for (int j = 0; j < 4; ++j)
            bf[j] = *(const short8*)&Bsh[(wn * 64 + j * 16 + l16) * 32 + quad * 8];
        #pragma unroll
        for (int i = 0; i < 4; ++i)
            #pragma unroll
            for (int j = 0; j < 4; ++j)
                if (jv[j])
                    acc[i][j] = __builtin_amdgcn_mfma_f32_16x16x32_bf16(af[i], bf[j], acc[i][j], 0, 0, 0);
    }
    #pragma unroll
    for (int i = 0; i < 4; ++i) {
        #pragma unroll
        for (int j = 0; j < 4; ++j) {
            if (!jv[j]) continue;
            int col = nblk + wn * 64 + j * 16 + l16;
            #pragma unroll
            for (int r = 0; r < 4; ++r) {
                int row = mblk + wm * 64 + i * 16 + quad * 4 + r;
                C[(size_t)row * N + col] = f2b(acc[i][j][r]);
            }
        }
    }
}

// ---------------- gemm128 variant: K=256, N=1024, split outputs at col 512 ----------------
__global__ void __launch_bounds__(256, 4)
gemm128_split(const ushort_t* __restrict__ A,
              const ushort_t* __restrict__ W,
              ushort_t* __restrict__ outX,   // cols 0..511
              ushort_t* __restrict__ outZ) { // cols 512..1023
    const int K = 256;
    __shared__ ushort_t Ash[128 * 32];
    __shared__ ushort_t Bsh[128 * 32];
    int tid = threadIdx.x;
    int lane = tid & 63, widx = tid >> 6;
    int wm = widx & 1, wn = widx >> 1;
    int l16 = lane & 15, quad = lane >> 4;
    int mblk = blockIdx.x * 128, nblk = blockIdx.y * 128;
    f32x4 acc[4][4];
    #pragma unroll
    for (int i = 0; i < 4; ++i)
        #pragma unroll
        for (int j = 0; j < 4; ++j)
            acc[i][j] = f32x4{0.0f, 0.0f, 0.0f, 0.0f};
    int srow = tid >> 2;
    int sseg = (tid & 3) * 8;
    for (int k0 = 0; k0 < K; k0 += 32) {
        __syncthreads();
        #pragma unroll
        for (int q = 0; q < 2; ++q) {
            int row = q * 64 + srow;
            gload16(&A[(size_t)(mblk + row) * K + k0 + sseg], &Ash[row * 32 + sseg]);
            gload16(&W[(size_t)(nblk + row) * K + k0 + sseg], &Bsh[row * 32 + sseg]);
        }
        __syncthreads();
        short8 af[4], bf[4];
        #pragma unroll
        for (int i = 0; i < 4; ++i)
            af[i] = *(const short8*)&Ash[(wm * 64 + i * 16 + l16) * 32 + quad * 8];
        #pragma unroll
        for (int j = 0; j < 4; ++j)
            bf[j] = *(const short8*)&Bsh[(wn * 64 + j * 16 + l16) * 32 + quad * 8];
        #pragma unroll
        for (int i = 0; i < 4; ++i)
            #pragma unroll
            for (int j = 0; j < 4; ++j)
                acc[i][j] = __builtin_amdgcn_mfma_f32_16x16x32_bf16(af[i], bf[j], acc[i][j], 0, 0, 0);
    }
    #pragma unroll
    for (int i = 0; i < 4; ++i) {
        #pragma unroll
        for (int j = 0; j < 4; ++j) {
            int colg = nblk + wn * 64 + j * 16 + l16;    // tile never straddles 512
            ushort_t* dst = (colg < 512) ? outX : outZ;
            int col = colg & 511;
            #pragma unroll
            for (int r = 0; r < 4; ++r) {
                int row = mblk + wm * 64 + i * 16 + quad * 4 + r;
                dst[(size_t)row * 512 + col] = f2b(acc[i][j][r]);
            }
        }
    }
}

// ---------------- tiled conv(4)+SiLU: all-coalesced, dual output ----------------
__global__ void conv_silu_t(const ushort_t* __restrict__ xh,
                            const float* __restrict__ cw,
                            const float* __restrict__ cb,
                            ushort_t* __restrict__ xc,
                            ushort_t* __restrict__ u_T) {
    int bt0 = blockIdx.x * 64;
    int d0  = blockIdx.y * 64;
    int b   = bt0 >> 12;
    int t0  = bt0 & 4095;
    __shared__ ushort_t tin[67][66];
    __shared__ ushort_t tout[64][66];
    int tid = threadIdx.x, lane = tid & 63, widx = tid >> 6;
    for (int r = widx; r < 67; r += 4) {
        int tt = t0 - 3 + r;
        tin[r][lane] = (tt >= 0) ? xh[((size_t)bt0 - 3 + r) * 512 + d0 + lane] : (ushort_t)0;
    }
    __syncthreads();
    for (int dd = widx; dd < 64; dd += 4) {
        int d = d0 + dd;
        float acc = cb[d];
        #pragma unroll
        for (int k = 0; k < 4; ++k)
            acc += cw[d * 4 + k] * b2f(tin[lane + k][dd]);
        float s = acc / (1.0f + __expf(-acc));
        ushort_t o = f2b(s);
        u_T[((size_t)b * 512 + d) * 4096 + t0 + lane] = o;
        tout[lane][dd] = o;
    }
    __syncthreads();
    for (int r = widx; r < 64; r += 4)
        xc[((size_t)bt0 + r) * 512 + d0 + lane] = tout[r][lane];
}

// ---------------- tiled dt/w (+fused B/C pair-interleaved + state-permuted unpack) ----------------
// BCfI layout: [pair=bt/2][slot] as f32x4 (B_e,C_e,B_o,C_o), where slot p holds
// STATE perm_inv(p) — bakes the scan's lane-bit permutation into the data.
__global__ void dt_sp_t(const ushort_t* __restrict__ xdbl,
                        const float* __restrict__ wdt,
                        const float* __restrict__ bdt,
                        const ushort_t* __restrict__ u_T,
                        ushort_t* __restrict__ dt_T,
                        ushort_t* __restrict__ w_T,
                        f32x4* __restrict__ BCfI) {
    int bt0 = blockIdx.x * 64;
    int d0  = blockIdx.y * 64;
    int b   = bt0 >> 12;
    int t0  = bt0 & 4095;
    __shared__ float din[64][17];
    int tid = threadIdx.x;
    for (int i = tid; i < 64 * 16; i += 256) {
        int r = i >> 4, k = i & 15;
        din[r][k] = b2f(xdbl[((size_t)bt0 + r) * 144 + k]);
    }
    __syncthreads();
    int lane = tid & 63, widx = tid >> 6;
    for (int dd = widx; dd < 64; dd += 4) {
        int d = d0 + dd;
        float acc = bdt[d];
        #pragma unroll
        for (int k = 0; k < 16; ++k)
            acc += din[lane][k] * wdt[d * 16 + k];
        float sp = (acc > 20.0f) ? acc : log1pf(__expf(acc));
        size_t idx = ((size_t)b * 512 + d) * 4096 + t0 + lane;
        dt_T[idx] = f2b(sp);
        float uvv = b2f(u_T[idx]);
        w_T[idx] = f2b(sp * uvv);
    }
    // fused B/C unpack, pair-interleaved + state-permuted
    if (blockIdx.y == 0) {
        for (int i = tid; i < 32 * 64; i += 256) {
            int p = i >> 6, s = i & 63;
            int sg = perm_inv(s);                 // state stored at slot s
            const ushort_t* rpe = xdbl + ((size_t)bt0 + 2 * p) * 144;
            const ushort_t* rpo = rpe + 144;
            f32x4 v;
            v.x = b2f(rpe[16 + sg]); v.y = b2f(rpe[80 + sg]);
            v.z = b2f(rpo[16 + sg]); v.w = b2f(rpo[80 + sg]);
            BCfI[((size_t)(bt0 >> 1) + p) * 64 + s] = v;
        }
    }
}

// ---------------- selective scan v15 ----------------
// vs v14: (1) asm prefetch outputs now EARLY-CLOBBER ("=&v") — v14's plain
// "=v" let the allocator alias pr0..3 with the g1 address pair, corrupting
// addresses mid-block (the crash). (2) bit-permuted merge tree: level->xor
// distance remapped {1,2,8,16,32,4} so the 12 DS-pipe shfl_xor merges/slab
// (xor4/xor8 at lvl2/3) become VALU DPP row_ror:8 / permlane16_swap; only
// ONE DS-pipe merge (xor4, lvl5) remains per slab. State slots and y/u lane
// indices permuted consistently (perm_inv); dt/w reads are lane-uniform.
template<int LVL>
__device__ __forceinline__ float merge_lvl_t(float left, float right, int lane) {
    // physical xor distance per level: lvl0->1(bit0), lvl1->2(bit1),
    // lvl2->8(bit3), lvl5->4(bit2)
    constexpr int XBIT = (LVL == 0) ? 0 : (LVL == 1) ? 1 : (LVL == 2) ? 3 : 2;
    bool bit = (lane >> XBIT) & 1;
    float send = bit ? left : right;
    float keep = bit ? right : left;
    float recv;
    if constexpr (LVL == 0)
        recv = __int_as_float(__builtin_amdgcn_update_dpp(
            0, __float_as_int(send), 0xB1, 0xF, 0xF, false));   // quad_perm xor1
    else if constexpr (LVL == 1)
        recv = __int_as_float(__builtin_amdgcn_update_dpp(
            0, __float_as_int(send), 0x4E, 0xF, 0xF, false));   // quad_perm xor2
    else if constexpr (LVL == 2)
        recv = __int_as_float(__builtin_amdgcn_update_dpp(
            0, __float_as_int(send), 0x128, 0xF, 0xF, false));  // row_ror:8 == xor8
    else
        recv = __shfl_xor(send, 4, 64);                         // xor4 (1x/slab)
    return keep + recv;
}
// xor16 merge: [L0+L1, R0+R1, ...] interleave (HW-verified v11/v13)
__device__ __forceinline__ float merge16_swap(float a, float b) {
    asm volatile("s_nop 1\n\tv_permlane16_swap_b32 %0, %1" : "+v"(a), "+v"(b));
    return a + b;
}
// xor32 merge (HW-verified v11/v13)
__device__ __forceinline__ float merge32_swap(float a, float b) {
    asm volatile("s_nop 1\n\tv_permlane32_swap_b32 %0, %1" : "+v"(a), "+v"(b));
    return a + b;
}

__global__ void __launch_bounds__(256, 4)
scan15(const ushort_t* __restrict__ dt_T,
       ushort_t* uT_ysT,
       const ushort_t* __restrict__ w_T,
       const f32x4* __restrict__ BCfI,
       const float* __restrict__ Alog,
       const float* __restrict__ Dp) {
    __shared__ f32x4 BCsh[32][64];   // [pair][slot]: (B_e, C_e, B_o, C_o), slot-permuted
    int tid = threadIdx.x;
    int lane = tid & 63, widx = tid >> 6;
    int wid = blockIdx.x * 4 + widx;
    int b = wid >> 9, d = wid & 511;
    int pinv = perm_inv(lane);       // this lane's state index / time index
    float a2 = -__expf(Alog[d * 64 + pinv]) * 1.442695041f;   // log2(e) folded
    float Dd = Dp[d];
    float h = 0.0f;
    size_t rowT = ((size_t)b * 512 + d) * 4096;
    uint_t rowTu = __builtin_amdgcn_readfirstlane((uint_t)rowT);
    size_t base = (size_t)b * LSEQ;
    size_t woff = (size_t)widx * 8192 + (size_t)lane * 16;

    // prolog: async direct stage of slab 0, then drain
    {
        const char* gsrc = (const char*)BCfI + base * 512;
        char* ldst = (char*)&BCsh[0][0];
        #pragma unroll
        for (int it = 0; it < 8; ++it)
            gload16(gsrc + woff + (size_t)it * 1024, ldst + woff + (size_t)it * 1024);
    }
    __syncthreads();

    #pragma unroll 1
    for (int sl = 0; sl < 64; ++sl) {
        int t0 = sl * 64;
        // T14: next slab's 8x16B as unmovable asm loads (EARLY-CLOBBER outputs)
        f32x4 pr0, pr1, pr2, pr3, pr4, pr5, pr6, pr7;
        if (sl < 63) {
            const char* g0 = (const char*)BCfI + (size_t)(base + t0 + 64) * 512 + woff;
            const char* g1 = g0 + 4096;
            asm volatile(
                "global_load_dwordx4 %0, %8, off\n\t"
                "global_load_dwordx4 %1, %8, off offset:1024\n\t"
                "global_load_dwordx4 %2, %8, off offset:2048\n\t"
                "global_load_dwordx4 %3, %8, off offset:3072\n\t"
                "global_load_dwordx4 %4, %9, off\n\t"
                "global_load_dwordx4 %5, %9, off offset:1024\n\t"
                "global_load_dwordx4 %6, %9, off offset:2048\n\t"
                "global_load_dwordx4 %7, %9, off offset:3072"
                : "=&v"(pr0), "=&v"(pr1), "=&v"(pr2), "=&v"(pr3),
                  "=&v"(pr4), "=&v"(pr5), "=&v"(pr6), "=&v"(pr7)
                : "v"(g0), "v"(g1)
                : "memory");
        }
        const uint_t* dtw = (const uint_t*)(dt_T + rowTu) + (t0 >> 1);
        const uint_t* wwp = (const uint_t*)(w_T + rowTu) + (t0 >> 1);
        float uv = b2f(uT_ysT[rowT + t0 + pinv]);
        float acc[4], s4, s5, yfin = 0.0f, v16 = 0.0f;
        f32x4 qb;
        #pragma unroll 1
        for (int j1 = 0; j1 < 4; ++j1) {
            #pragma unroll
            for (int jj = 0; jj < 16; ++jj) {
                int j = j1 * 16 + jj;
                uint_t pd = dtw[j >> 1];
                uint_t pw = wwp[j >> 1];
                float sdt = __uint_as_float((jj & 1) ? (pd & 0xFFFF0000u) : (pd << 16));
                float sw  = __uint_as_float((jj & 1) ? (pw & 0xFFFF0000u) : (pw << 16));
                if ((jj & 1) == 0) qb = BCsh[j >> 1][lane];    // ds_read_b128 / 2 steps
                float bcx = (jj & 1) ? qb.z : qb.x;
                float bcy = (jj & 1) ? qb.w : qb.y;
                float dA = __builtin_amdgcn_exp2f(sdt * a2);   // raw v_exp_f32
                h = dA * h + sw * bcx;
                float v = h * bcy;
                const int dest = (jj == 15) ? 4 : __builtin_ctz(~(unsigned)jj);
                if (0 < dest) v = merge_lvl_t<0>(acc[0], v, lane);
                if (1 < dest) v = merge_lvl_t<1>(acc[1], v, lane);
                if (2 < dest) v = merge_lvl_t<2>(acc[2], v, lane);
                if (3 < dest) v = merge16_swap(acc[3], v);     // xor16 (VALU)
                if (jj == 15) v16 = v;
                else acc[dest] = v;
            }
            if ((j1 & 1) == 0) {
                s4 = v16;
            } else {
                float m = merge32_swap(s4, v16);               // lvl4: xor32 (VALU)
                if (j1 == 1) s5 = m;
                else yfin = merge_lvl_t<5>(s5, m, lane);       // lvl5: xor4 (1 DS op)
            }
        }
        float y = yfin + uv * Dd;
        uT_ysT[rowT + t0 + pinv] = f2b(y);
        __syncthreads();             // all waves done READING BCsh
        if (sl < 63) {
            asm volatile("s_waitcnt vmcnt(0)" ::: "memory");
            char* ldst = (char*)&BCsh[0][0] + woff;
            *(f32x4*)(ldst + 0)    = pr0;
            *(f32x4*)(ldst + 1024) = pr1;
            *(f32x4*)(ldst + 2048) = pr2;
            *(f32x4*)(ldst + 3072) = pr3;
            *(f32x4*)(ldst + 4096) = pr4;
            *(f32x4*)(ldst + 5120) = pr5;
            *(f32x4*)(ldst + 6144) = pr6;
            *(f32x4*)(ldst + 7168) = pr7;
        }
        __syncthreads();             // LDS refilled for next slab
    }
}

// ---------------- gate + transpose: ys[bt,d] = ysT[b,d,t] * silu(z[bt,d]) ----------------
__global__ void gate_t(const ushort_t* __restrict__ ysT,
                       const ushort_t* __restrict__ zb,
                       ushort_t* __restrict__ ys) {
    int bt0 = blockIdx.x * 64;
    int d0  = blockIdx.y * 64;
    int b   = bt0 >> 12;
    int t0  = bt0 & 4095;
    __shared__ ushort_t tile[64][66];
    int tid = threadIdx.x, lane = tid & 63, widx = tid >> 6;
    for (int dd = widx; dd < 64; dd += 4)
        tile[dd][lane] = ysT[((size_t)b * 512 + d0 + dd) * 4096 + t0 + lane];
    __syncthreads();
    for (int r = widx; r < 64; r += 4) {
        float zv = b2f(zb[((size_t)bt0 + r) * 512 + d0 + lane]);
        float yv = b2f(tile[lane][r]);
        float g = zv / (1.0f + __expf(-zv));
        ys[((size_t)bt0 + r) * 512 + d0 + lane] = f2b(yv * g);
    }
}

// ---------------- final LN + transpose-combine + residual (fp32 out) ----------------
__global__ void final_ln_add(const ushort_t* __restrict__ outm,
                             const float* __restrict__ x,
                             const float* __restrict__ w,
                             const float* __restrict__ bb,
                             float* __restrict__ out) {
    int row = blockIdx.x;
    int c = threadIdx.x;
    int b = row >> 12, l = row & 4095, i = l >> 6, j = l & 63;
    size_t rA = ((size_t)b * LSEQ + l) * DIMC;
    size_t rB = ((size_t)(4 + b) * LSEQ + (j * 64 + i)) * DIMC;
    float va = b2f(outm[rA + c]);
    float vb = b2f(outm[rB + c]);
    float s1 = va, s2 = va * va, s3 = vb, s4 = vb * vb;
    for (int off = 32; off; off >>= 1) {
        s1 += __shfl_xor(s1, off, 64);
        s2 += __shfl_xor(s2, off, 64);
        s3 += __shfl_xor(s3, off, 64);
        s4 += __shfl_xor(s4, off, 64);
    }
    __shared__ float sm[4][4];
    int widx = c >> 6, lane = c & 63;
    if (lane == 0) { sm[widx][0] = s1; sm[widx][1] = s2; sm[widx][2] = s3; sm[widx][3] = s4; }
    __syncthreads();
    s1 = sm[0][0] + sm[1][0] + sm[2][0] + sm[3][0];
    s2 = sm[0][1] + sm[1][1] + sm[2][1] + sm[3][1];
    s3 = sm[0][2] + sm[1][2] + sm[2][2] + sm[3][2];
    s4 = sm[0][3] + sm[1][3] + sm[2][3] + sm[3][3];
    float muA = s1 * (1.0f / 256.0f), varA = s2 * (1.0f / 256.0f) - muA * muA;
    float muB = s3 * (1.0f / 256.0f), varB = s4 * (1.0f / 256.0f) - muB * muB;
    float lw = w[c], lb = bb[c];
    float ya = (va - muA) * rsqrtf(varA + 1e-6f) * lw + lb;
    float yb = (vb - muB) * rsqrtf(varB + 1e-6f) * lw + lb;
    float xo = x[(size_t)row * DIMC + c];
    out[(size_t)row * DIMC + c] = xo + ya + yb;
}

extern "C" void kernel_launch(void* const* d_in, const int* in_sizes, int n_in,
                              void* d_out, int out_size, void* d_ws, size_t ws_size,
                              hipStream_t stream) {
    const float* x      = (const float*)d_in[0];
    const float* ln1_w  = (const float*)d_in[1];
    const float* ln1_b  = (const float*)d_in[2];
    const float* ln2_w  = (const float*)d_in[3];
    const float* ln2_b  = (const float*)d_in[4];
    const float* W_in   = (const float*)d_in[5];
    const float* conv_w = (const float*)d_in[6];
    const float* conv_b = (const float*)d_in[7];
    const float* W_x    = (const float*)d_in[8];
    const float* W_dt   = (const float*)d_in[9];
    const float* b_dt   = (const float*)d_in[10];
    const float* A_log  = (const float*)d_in[11];
    const float* D_par  = (const float*)d_in[12];
    const float* W_out  = (const float*)d_in[13];
    float* out = (float*)d_out;

    // ---- workspace (~169 MB) ----
    char* ws = (char*)d_ws;
    size_t off = 0;
    ushort_t* wb_in  = (ushort_t*)(ws + off); off += (size_t)1024 * 256 * 2;
    ushort_t* wb_x   = (ushort_t*)(ws + off); off += (size_t)144 * 512 * 2;
    ushort_t* wb_out = (ushort_t*)(ws + off); off += (size_t)256 * 512 * 2;
    const size_t R0 = (size_t)MROWS * DIMC * 2;
    const size_t R1 = (size_t)MROWS * 512 * 2;
    ushort_t* r0 = (ushort_t*)(ws + off); off += R0;   // xm -> xdbl -> outm
    ushort_t* r1 = (ushort_t*)(ws + off); off += R1;   // xhalf -> dt_T
    ushort_t* r2 = (ushort_t*)(ws + off); off += R1;   // z
    ushort_t* r3 = (ushort_t*)(ws + off); off += R1;   // xc -> w_T -> ys
    ushort_t* r4 = (ushort_t*)(ws + off); off += R1;   // u_T -> ysT (in place)
    f32x4*    BCfI = (f32x4*)(ws + off);  off += (size_t)MROWS * 64 * 8;  // 16.8 MB

    ushort_t* xm    = r0;
    ushort_t* xdbl  = r0;
    ushort_t* outm  = r0;
    ushort_t* xhalf = r1;
    ushort_t* dt_T  = r1;
    ushort_t* zb    = r2;
    ushort_t* xc    = r3;
    ushort_t* w_T   = r3;
    ushort_t* ys    = r3;
    ushort_t* u_T   = r4;

    // 0. convert MFMA weights fp32 -> bf16 (one launch)
    const int ncvt = 1024 * 256 + 144 * 512 + 256 * 512;
    hipLaunchKernelGGL(cvtw3, dim3((ncvt + 255) / 256), dim3(256), 0, stream,
                       W_in, wb_in, W_x, wb_x, W_out, wb_out);

    // A. LayerNorm + dual-order xm
    hipLaunchKernelGGL(ln1_build_xm, dim3(4 * LSEQ), dim3(256), 0, stream,
                       x, ln1_w, ln1_b, xm);
    // B. one launch: cols<512 -> xhalf, cols>=512 -> zb
    hipLaunchKernelGGL(gemm128_split, dim3(MROWS / 128, 8), dim3(256), 0, stream,
                       xm, wb_in, xhalf, zb);
    // C. tiled conv + SiLU: xhalf -> xc[bt,d] + u_T[b,d,t]
    hipLaunchKernelGGL(conv_silu_t, dim3(MROWS / 64, 8), dim3(256), 0, stream,
                       xhalf, conv_w, conv_b, xc, u_T);
    // D. x_dbl = xc @ W_x^T   (N=144, K=512)
    hipLaunchKernelGGL(gemm128, dim3(MROWS / 128, 2), dim3(256), 0, stream,
                       xc, wb_x, xdbl, MROWS, 144, 512);
    // E. dt/w (+ pair-interleaved, state-permuted B/C unpack)
    hipLaunchKernelGGL(dt_sp_t, dim3(MROWS / 64, 8), dim3(256), 0, stream,
                       xdbl, W_dt, b_dt, u_T, dt_T, w_T, BCfI);
    // F. selective scan v15: u_T -> ysT in place
    hipLaunchKernelGGL(scan15, dim3(BS2 * 512 / 4), dim3(256), 0, stream,
                       dt_T, u_T, w_T, BCfI, A_log, D_par);
    // G. gate + transpose: ys[bt,d] = ysT * silu(z)
    hipLaunchKernelGGL(gate_t, dim3(MROWS / 64, 8), dim3(256), 0, stream,
                       u_T, zb, ys);
    // H. outm = ys @ W_out^T   (N=256, K=512)
    hipLaunchKernelGGL(gemm128, dim3(MROWS / 128, 2), dim3(256), 0, stream,
                       ys, wb_out, outm, MROWS, 256, 512);
    // I. final LN + transpose combine + residual (fp32 out)
    hipLaunchKernelGGL(final_ln_add, dim3(4 * LSEQ), dim3(256), 0, stream,
                       outm, x, ln2_w, ln2_b, out);
}

// Round 6
// 689.451 us; speedup vs baseline: 1.2324x; 1.0252x over previous
//
#include <hip/hip_runtime.h>
#include <hip/hip_bf16.h>

typedef unsigned short ushort_t;
typedef unsigned int uint_t;
typedef __attribute__((ext_vector_type(8))) short short8;
typedef __attribute__((ext_vector_type(4))) float f32x4;

#define DIMC 256
#define D_INNER 512
#define D_STATE 64
#define DT_RANK 16
#define LSEQ 4096
#define BS2 8            // 2*BS batches through mamba
#define MROWS (BS2*LSEQ) // 32768

// lane-bit permutation for the scan merge tree:
// t-bit b -> lane-xor bit pi(b): pi = {0,1,3,4,5,2}
// Pinv(p): t = (p&3) | ((p&0x38)>>1) | ((p&4)<<3)
__device__ __forceinline__ int perm_inv(int p) {
    return (p & 3) | ((p & 0x38) >> 1) | ((p & 4) << 3);
}

__device__ __forceinline__ float b2f(ushort_t u) {
    union { uint_t i; float f; } v; v.i = ((uint_t)u) << 16; return v.f;
}
__device__ __forceinline__ ushort_t f2b(float f) {
    union { float f; uint_t i; } v; v.f = f;
    uint_t r = v.i + 0x7FFFu + ((v.i >> 16) & 1u);   // RNE
    return (ushort_t)(r >> 16);
}

// async global->LDS 16B per lane (HW: wave-uniform LDS base + lane*16)
typedef __attribute__((address_space(1))) const unsigned int gas_u32;
typedef __attribute__((address_space(3))) unsigned int las_u32;
__device__ __forceinline__ void gload16(const void* g, void* l) {
    __builtin_amdgcn_global_load_lds((gas_u32*)g, (las_u32*)l, 16, 0, 0);
}

// ---------------- fp32 -> bf16 conversion of the 3 MFMA weight mats ----------------
__global__ void cvtw3(const float* __restrict__ s0, ushort_t* __restrict__ d0,
                      const float* __restrict__ s1, ushort_t* __restrict__ d1,
                      const float* __restrict__ s2, ushort_t* __restrict__ d2) {
    int i = blockIdx.x * 256 + threadIdx.x;
    const int n0 = 1024 * 256, n1 = 144 * 512, n2 = 256 * 512;
    if (i < n0) d0[i] = f2b(s0[i]);
    else if (i < n0 + n1) d1[i - n0] = f2b(s1[i - n0]);
    else if (i < n0 + n1 + n2) d2[i - n0 - n1] = f2b(s2[i - n0 - n1]);
}

// ---------------- LN1 + build xm (both orders), fp32 in, bf16 out ----------------
__global__ void ln1_build_xm(const float* __restrict__ x,
                             const float* __restrict__ w,
                             const float* __restrict__ bb,
                             ushort_t* __restrict__ xm) {
    int row = blockIdx.x;            // b*4096 + l  (b in 0..3)
    int c = threadIdx.x;             // 0..255
    float v = x[(size_t)row * DIMC + c];
    float s1 = v, s2 = v * v;
    for (int off = 32; off; off >>= 1) {
        s1 += __shfl_xor(s1, off, 64);
        s2 += __shfl_xor(s2, off, 64);
    }
    __shared__ float sa[4], sb[4];
    int widx = c >> 6, lane = c & 63;
    if (lane == 0) { sa[widx] = s1; sb[widx] = s2; }
    __syncthreads();
    s1 = sa[0] + sa[1] + sa[2] + sa[3];
    s2 = sb[0] + sb[1] + sb[2] + sb[3];
    float mu = s1 * (1.0f / 256.0f);
    float var = s2 * (1.0f / 256.0f) - mu * mu;
    float xn = (v - mu) * rsqrtf(var + 1e-6f) * w[c] + bb[c];
    ushort_t o = f2b(xn);
    int b = row >> 12, l = row & 4095, i = l >> 6, j = l & 63;
    xm[((size_t)b * LSEQ + l) * DIMC + c] = o;
    xm[((size_t)(4 + b) * LSEQ + (j * 64 + i)) * DIMC + c] = o;
}

// ---------------- 128x128 LDS-tiled NT GEMM with global_load_lds staging ----------------
__global__ void __launch_bounds__(256, 4)
gemm128(const ushort_t* __restrict__ A,
        const ushort_t* __restrict__ W,
        ushort_t* __restrict__ C, int M, int N, int K) {
    __shared__ ushort_t Ash[128 * 32];
    __shared__ ushort_t Bsh[128 * 32];
    int tid = threadIdx.x;
    int lane = tid & 63, widx = tid >> 6;
    int wm = widx & 1, wn = widx >> 1;
    int l16 = lane & 15, quad = lane >> 4;
    int mblk = blockIdx.x * 128, nblk = blockIdx.y * 128;
    f32x4 acc[4][4];
    #pragma unroll
    for (int i = 0; i < 4; ++i)
        #pragma unroll
        for (int j = 0; j < 4; ++j)
            acc[i][j] = f32x4{0.0f, 0.0f, 0.0f, 0.0f};
    int srow = tid >> 2;
    int sseg = (tid & 3) * 8;
    bool jv[4];
    #pragma unroll
    for (int j = 0; j < 4; ++j) jv[j] = (nblk + wn * 64 + j * 16) < N;

    for (int k0 = 0; k0 < K; k0 += 32) {
        __syncthreads();
        #pragma unroll
        for (int q = 0; q < 2; ++q) {
            int row = q * 64 + srow;
            gload16(&A[(size_t)(mblk + row) * K + k0 + sseg], &Ash[row * 32 + sseg]);
            gload16(&W[(size_t)(nblk + row) * K + k0 + sseg], &Bsh[row * 32 + sseg]);
        }
        __syncthreads();
        short8 af[4], bf[4];
        #pragma unroll
        for (int i = 0; i < 4; ++i)
            af[i] = *(const short8*)&Ash[(wm * 64 + i * 16 + l16) * 32 + quad * 8];
        #pragma unroll
        for (int j = 0; j < 4; ++j)
            bf[j] = *(const short8*)&Bsh[(wn * 64 + j * 16 + l16) * 32 + quad * 8];
        #pragma unroll
        for (int i = 0; i < 4; ++i)
            #pragma unroll
            for (int j = 0; j < 4; ++j)
                if (jv[j])
                    acc[i][j] = __builtin_amdgcn_mfma_f32_16x16x32_bf16(af[i], bf[j], acc[i][j], 0, 0, 0);
    }
    #pragma unroll
    for (int i = 0; i < 4; ++i) {
        #pragma unroll
        for (int j = 0; j < 4; ++j) {
            if (!jv[j]) continue;
            int col = nblk + wn * 64 + j * 16 + l16;
            #pragma unroll
            for (int r = 0; r < 4; ++r) {
                int row = mblk + wm * 64 + i * 16 + quad * 4 + r;
                C[(size_t)row * N + col] = f2b(acc[i][j][r]);
            }
        }
    }
}

// ---------------- gemm128 variant: K=256, N=1024, split outputs at col 512 ----------------
__global__ void __launch_bounds__(256, 4)
gemm128_split(const ushort_t* __restrict__ A,
              const ushort_t* __restrict__ W,
              ushort_t* __restrict__ outX,   // cols 0..511
              ushort_t* __restrict__ outZ) { // cols 512..1023
    const int K = 256;
    __shared__ ushort_t Ash[128 * 32];
    __shared__ ushort_t Bsh[128 * 32];
    int tid = threadIdx.x;
    int lane = tid & 63, widx = tid >> 6;
    int wm = widx & 1, wn = widx >> 1;
    int l16 = lane & 15, quad = lane >> 4;
    int mblk = blockIdx.x * 128, nblk = blockIdx.y * 128;
    f32x4 acc[4][4];
    #pragma unroll
    for (int i = 0; i < 4; ++i)
        #pragma unroll
        for (int j = 0; j < 4; ++j)
            acc[i][j] = f32x4{0.0f, 0.0f, 0.0f, 0.0f};
    int srow = tid >> 2;
    int sseg = (tid & 3) * 8;
    for (int k0 = 0; k0 < K; k0 += 32) {
        __syncthreads();
        #pragma unroll
        for (int q = 0; q < 2; ++q) {
            int row = q * 64 + srow;
            gload16(&A[(size_t)(mblk + row) * K + k0 + sseg], &Ash[row * 32 + sseg]);
            gload16(&W[(size_t)(nblk + row) * K + k0 + sseg], &Bsh[row * 32 + sseg]);
        }
        __syncthreads();
        short8 af[4], bf[4];
        #pragma unroll
        for (int i = 0; i < 4; ++i)
            af[i] = *(const short8*)&Ash[(wm * 64 + i * 16 + l16) * 32 + quad * 8];
        #pragma unroll
        for (int j = 0; j < 4; ++j)
            bf[j] = *(const short8*)&Bsh[(wn * 64 + j * 16 + l16) * 32 + quad * 8];
        #pragma unroll
        for (int i = 0; i < 4; ++i)
            #pragma unroll
            for (int j = 0; j < 4; ++j)
                acc[i][j] = __builtin_amdgcn_mfma_f32_16x16x32_bf16(af[i], bf[j], acc[i][j], 0, 0, 0);
    }
    #pragma unroll
    for (int i = 0; i < 4; ++i) {
        #pragma unroll
        for (int j = 0; j < 4; ++j) {
            int colg = nblk + wn * 64 + j * 16 + l16;    // tile never straddles 512
            ushort_t* dst = (colg < 512) ? outX : outZ;
            int col = colg & 511;
            #pragma unroll
            for (int r = 0; r < 4; ++r) {
                int row = mblk + wm * 64 + i * 16 + quad * 4 + r;
                dst[(size_t)row * 512 + col] = f2b(acc[i][j][r]);
            }
        }
    }
}

// ---------------- tiled conv(4)+SiLU: all-coalesced, dual output ----------------
__global__ void conv_silu_t(const ushort_t* __restrict__ xh,
                            const float* __restrict__ cw,
                            const float* __restrict__ cb,
                            ushort_t* __restrict__ xc,
                            ushort_t* __restrict__ u_T) {
    int bt0 = blockIdx.x * 64;
    int d0  = blockIdx.y * 64;
    int b   = bt0 >> 12;
    int t0  = bt0 & 4095;
    __shared__ ushort_t tin[67][66];
    __shared__ ushort_t tout[64][66];
    int tid = threadIdx.x, lane = tid & 63, widx = tid >> 6;
    for (int r = widx; r < 67; r += 4) {
        int tt = t0 - 3 + r;
        tin[r][lane] = (tt >= 0) ? xh[((size_t)bt0 - 3 + r) * 512 + d0 + lane] : (ushort_t)0;
    }
    __syncthreads();
    for (int dd = widx; dd < 64; dd += 4) {
        int d = d0 + dd;
        float acc = cb[d];
        #pragma unroll
        for (int k = 0; k < 4; ++k)
            acc += cw[d * 4 + k] * b2f(tin[lane + k][dd]);
        float s = acc / (1.0f + __expf(-acc));
        ushort_t o = f2b(s);
        u_T[((size_t)b * 512 + d) * 4096 + t0 + lane] = o;
        tout[lane][dd] = o;
    }
    __syncthreads();
    for (int r = widx; r < 64; r += 4)
        xc[((size_t)bt0 + r) * 512 + d0 + lane] = tout[r][lane];
}

// ---------------- tiled dt/w (+fused B/C pair-interleaved + state-permuted unpack) ----------------
// BCfI layout: [pair=bt/2][slot] as f32x4 (B_e,C_e,B_o,C_o), where slot p holds
// STATE perm_inv(p) — bakes the scan's lane-bit permutation into the data.
__global__ void dt_sp_t(const ushort_t* __restrict__ xdbl,
                        const float* __restrict__ wdt,
                        const float* __restrict__ bdt,
                        const ushort_t* __restrict__ u_T,
                        ushort_t* __restrict__ dt_T,
                        ushort_t* __restrict__ w_T,
                        f32x4* __restrict__ BCfI) {
    int bt0 = blockIdx.x * 64;
    int d0  = blockIdx.y * 64;
    int b   = bt0 >> 12;
    int t0  = bt0 & 4095;
    __shared__ float din[64][17];
    int tid = threadIdx.x;
    for (int i = tid; i < 64 * 16; i += 256) {
        int r = i >> 4, k = i & 15;
        din[r][k] = b2f(xdbl[((size_t)bt0 + r) * 144 + k]);
    }
    __syncthreads();
    int lane = tid & 63, widx = tid >> 6;
    for (int dd = widx; dd < 64; dd += 4) {
        int d = d0 + dd;
        float acc = bdt[d];
        #pragma unroll
        for (int k = 0; k < 16; ++k)
            acc += din[lane][k] * wdt[d * 16 + k];
        float sp = (acc > 20.0f) ? acc : log1pf(__expf(acc));
        size_t idx = ((size_t)b * 512 + d) * 4096 + t0 + lane;
        dt_T[idx] = f2b(sp);
        float uvv = b2f(u_T[idx]);
        w_T[idx] = f2b(sp * uvv);
    }
    // fused B/C unpack, pair-interleaved + state-permuted
    if (blockIdx.y == 0) {
        for (int i = tid; i < 32 * 64; i += 256) {
            int p = i >> 6, s = i & 63;
            int sg = perm_inv(s);                 // state stored at slot s
            const ushort_t* rpe = xdbl + ((size_t)bt0 + 2 * p) * 144;
            const ushort_t* rpo = rpe + 144;
            f32x4 v;
            v.x = b2f(rpe[16 + sg]); v.y = b2f(rpe[80 + sg]);
            v.z = b2f(rpo[16 + sg]); v.w = b2f(rpo[80 + sg]);
            BCfI[((size_t)(bt0 >> 1) + p) * 64 + s] = v;
        }
    }
}

// ---------------- selective scan v16 ----------------
// vs v15: (1) qs[8] batched LDS reads per 16-step block — with only ~12 free
// VGPRs (44 total, 32 locked in pr) the compiler serialized the 8 ds_read_b128
// with a full mixed lgkmcnt(0) drain per read (SMEM dt/w completes out-of-order
// vs DS on the shared counter -> every wait is a drain). Batching gives ONE
// drain per 16 steps. (2) y-store deferred one slab (ypend) so the store-ack
// is not part of the pre-barrier vmcnt(0) drain.
template<int LVL>
__device__ __forceinline__ float merge_lvl_t(float left, float right, int lane) {
    // physical xor distance per level: lvl0->1(bit0), lvl1->2(bit1),
    // lvl2->8(bit3), lvl5->4(bit2)
    constexpr int XBIT = (LVL == 0) ? 0 : (LVL == 1) ? 1 : (LVL == 2) ? 3 : 2;
    bool bit = (lane >> XBIT) & 1;
    float send = bit ? left : right;
    float keep = bit ? right : left;
    float recv;
    if constexpr (LVL == 0)
        recv = __int_as_float(__builtin_amdgcn_update_dpp(
            0, __float_as_int(send), 0xB1, 0xF, 0xF, false));   // quad_perm xor1
    else if constexpr (LVL == 1)
        recv = __int_as_float(__builtin_amdgcn_update_dpp(
            0, __float_as_int(send), 0x4E, 0xF, 0xF, false));   // quad_perm xor2
    else if constexpr (LVL == 2)
        recv = __int_as_float(__builtin_amdgcn_update_dpp(
            0, __float_as_int(send), 0x128, 0xF, 0xF, false));  // row_ror:8 == xor8
    else
        recv = __shfl_xor(send, 4, 64);                         // xor4 (1x/slab)
    return keep + recv;
}
// xor16 merge: [L0+L1, R0+R1, ...] interleave (HW-verified v11/v13/v15)
__device__ __forceinline__ float merge16_swap(float a, float b) {
    asm volatile("s_nop 1\n\tv_permlane16_swap_b32 %0, %1" : "+v"(a), "+v"(b));
    return a + b;
}
// xor32 merge (HW-verified v11/v13/v15)
__device__ __forceinline__ float merge32_swap(float a, float b) {
    asm volatile("s_nop 1\n\tv_permlane32_swap_b32 %0, %1" : "+v"(a), "+v"(b));
    return a + b;
}

__global__ void __launch_bounds__(256, 4)
scan16(const ushort_t* __restrict__ dt_T,
       ushort_t* uT_ysT,
       const ushort_t* __restrict__ w_T,
       const f32x4* __restrict__ BCfI,
       const float* __restrict__ Alog,
       const float* __restrict__ Dp) {
    __shared__ f32x4 BCsh[32][64];   // [pair][slot]: (B_e, C_e, B_o, C_o), slot-permuted
    int tid = threadIdx.x;
    int lane = tid & 63, widx = tid >> 6;
    int wid = blockIdx.x * 4 + widx;
    int b = wid >> 9, d = wid & 511;
    int pinv = perm_inv(lane);       // this lane's state index / time index
    float a2 = -__expf(Alog[d * 64 + pinv]) * 1.442695041f;   // log2(e) folded
    float Dd = Dp[d];
    float h = 0.0f;
    size_t rowT = ((size_t)b * 512 + d) * 4096;
    uint_t rowTu = __builtin_amdgcn_readfirstlane((uint_t)rowT);
    size_t base = (size_t)b * LSEQ;
    size_t woff = (size_t)widx * 8192 + (size_t)lane * 16;

    // prolog: async direct stage of slab 0, then drain
    {
        const char* gsrc = (const char*)BCfI + base * 512;
        char* ldst = (char*)&BCsh[0][0];
        #pragma unroll
        for (int it = 0; it < 8; ++it)
            gload16(gsrc + woff + (size_t)it * 1024, ldst + woff + (size_t)it * 1024);
    }
    __syncthreads();

    ushort_t ypend = 0;
    #pragma unroll 1
    for (int sl = 0; sl < 64; ++sl) {
        int t0 = sl * 64;
        // T14: next slab's 8x16B as unmovable asm loads (early-clobber outputs)
        f32x4 pr0, pr1, pr2, pr3, pr4, pr5, pr6, pr7;
        if (sl < 63) {
            const char* g0 = (const char*)BCfI + (size_t)(base + t0 + 64) * 512 + woff;
            const char* g1 = g0 + 4096;
            asm volatile(
                "global_load_dwordx4 %0, %8, off\n\t"
                "global_load_dwordx4 %1, %8, off offset:1024\n\t"
                "global_load_dwordx4 %2, %8, off offset:2048\n\t"
                "global_load_dwordx4 %3, %8, off offset:3072\n\t"
                "global_load_dwordx4 %4, %9, off\n\t"
                "global_load_dwordx4 %5, %9, off offset:1024\n\t"
                "global_load_dwordx4 %6, %9, off offset:2048\n\t"
                "global_load_dwordx4 %7, %9, off offset:3072"
                : "=&v"(pr0), "=&v"(pr1), "=&v"(pr2), "=&v"(pr3),
                  "=&v"(pr4), "=&v"(pr5), "=&v"(pr6), "=&v"(pr7)
                : "v"(g0), "v"(g1)
                : "memory");
        }
        // deferred y store from previous slab (ack overlaps this slab's compute)
        if (sl) uT_ysT[rowT + t0 - 64 + pinv] = ypend;
        const uint_t* dtw = (const uint_t*)(dt_T + rowTu) + (t0 >> 1);
        const uint_t* wwp = (const uint_t*)(w_T + rowTu) + (t0 >> 1);
        float uv = b2f(uT_ysT[rowT + t0 + pinv]);
        float acc[4], s4, s5, yfin = 0.0f, v16 = 0.0f;
        #pragma unroll 1
        for (int j1 = 0; j1 < 4; ++j1) {
            // batched LDS reads: 8x ds_read_b128 issued together -> ONE lgkm
            // drain per 16 steps instead of one per pair
            f32x4 qs[8];
            #pragma unroll
            for (int q = 0; q < 8; ++q)
                qs[q] = BCsh[j1 * 8 + q][lane];
            #pragma unroll
            for (int jj = 0; jj < 16; ++jj) {
                int j = j1 * 16 + jj;
                uint_t pd = dtw[j >> 1];
                uint_t pw = wwp[j >> 1];
                float sdt = __uint_as_float((jj & 1) ? (pd & 0xFFFF0000u) : (pd << 16));
                float sw  = __uint_as_float((jj & 1) ? (pw & 0xFFFF0000u) : (pw << 16));
                float bcx = (jj & 1) ? qs[jj >> 1].z : qs[jj >> 1].x;
                float bcy = (jj & 1) ? qs[jj >> 1].w : qs[jj >> 1].y;
                float dA = __builtin_amdgcn_exp2f(sdt * a2);   // raw v_exp_f32
                h = dA * h + sw * bcx;
                float v = h * bcy;
                const int dest = (jj == 15) ? 4 : __builtin_ctz(~(unsigned)jj);
                if (0 < dest) v = merge_lvl_t<0>(acc[0], v, lane);
                if (1 < dest) v = merge_lvl_t<1>(acc[1], v, lane);
                if (2 < dest) v = merge_lvl_t<2>(acc[2], v, lane);
                if (3 < dest) v = merge16_swap(acc[3], v);     // xor16 (VALU)
                if (jj == 15) v16 = v;
                else acc[dest] = v;
            }
            if ((j1 & 1) == 0) {
                s4 = v16;
            } else {
                float m = merge32_swap(s4, v16);               // lvl4: xor32 (VALU)
                if (j1 == 1) s5 = m;
                else yfin = merge_lvl_t<5>(s5, m, lane);       // lvl5: xor4 (1 DS op)
            }
        }
        ypend = f2b(yfin + uv * Dd);
        __syncthreads();             // all waves done READING BCsh
        if (sl < 63) {
            asm volatile("s_waitcnt vmcnt(0)" ::: "memory");
            char* ldst = (char*)&BCsh[0][0] + woff;
            *(f32x4*)(ldst + 0)    = pr0;
            *(f32x4*)(ldst + 1024) = pr1;
            *(f32x4*)(ldst + 2048) = pr2;
            *(f32x4*)(ldst + 3072) = pr3;
            *(f32x4*)(ldst + 4096) = pr4;
            *(f32x4*)(ldst + 5120) = pr5;
            *(f32x4*)(ldst + 6144) = pr6;
            *(f32x4*)(ldst + 7168) = pr7;
        }
        __syncthreads();             // LDS refilled for next slab
    }
    uT_ysT[rowT + (LSEQ - 64) + pinv] = ypend;   // final slab's y
}

// ---------------- gate + transpose: ys[bt,d] = ysT[b,d,t] * silu(z[bt,d]) ----------------
__global__ void gate_t(const ushort_t* __restrict__ ysT,
                       const ushort_t* __restrict__ zb,
                       ushort_t* __restrict__ ys) {
    int bt0 = blockIdx.x * 64;
    int d0  = blockIdx.y * 64;
    int b   = bt0 >> 12;
    int t0  = bt0 & 4095;
    __shared__ ushort_t tile[64][66];
    int tid = threadIdx.x, lane = tid & 63, widx = tid >> 6;
    for (int dd = widx; dd < 64; dd += 4)
        tile[dd][lane] = ysT[((size_t)b * 512 + d0 + dd) * 4096 + t0 + lane];
    __syncthreads();
    for (int r = widx; r < 64; r += 4) {
        float zv = b2f(zb[((size_t)bt0 + r) * 512 + d0 + lane]);
        float yv = b2f(tile[lane][r]);
        float g = zv / (1.0f + __expf(-zv));
        ys[((size_t)bt0 + r) * 512 + d0 + lane] = f2b(yv * g);
    }
}

// ---------------- final LN + transpose-combine + residual (fp32 out) ----------------
__global__ void final_ln_add(const ushort_t* __restrict__ outm,
                             const float* __restrict__ x,
                             const float* __restrict__ w,
                             const float* __restrict__ bb,
                             float* __restrict__ out) {
    int row = blockIdx.x;
    int c = threadIdx.x;
    int b = row >> 12, l = row & 4095, i = l >> 6, j = l & 63;
    size_t rA = ((size_t)b * LSEQ + l) * DIMC;
    size_t rB = ((size_t)(4 + b) * LSEQ + (j * 64 + i)) * DIMC;
    float va = b2f(outm[rA + c]);
    float vb = b2f(outm[rB + c]);
    float s1 = va, s2 = va * va, s3 = vb, s4 = vb * vb;
    for (int off = 32; off; off >>= 1) {
        s1 += __shfl_xor(s1, off, 64);
        s2 += __shfl_xor(s2, off, 64);
        s3 += __shfl_xor(s3, off, 64);
        s4 += __shfl_xor(s4, off, 64);
    }
    __shared__ float sm[4][4];
    int widx = c >> 6, lane = c & 63;
    if (lane == 0) { sm[widx][0] = s1; sm[widx][1] = s2; sm[widx][2] = s3; sm[widx][3] = s4; }
    __syncthreads();
    s1 = sm[0][0] + sm[1][0] + sm[2][0] + sm[3][0];
    s2 = sm[0][1] + sm[1][1] + sm[2][1] + sm[3][1];
    s3 = sm[0][2] + sm[1][2] + sm[2][2] + sm[3][2];
    s4 = sm[0][3] + sm[1][3] + sm[2][3] + sm[3][3];
    float muA = s1 * (1.0f / 256.0f), varA = s2 * (1.0f / 256.0f) - muA * muA;
    float muB = s3 * (1.0f / 256.0f), varB = s4 * (1.0f / 256.0f) - muB * muB;
    float lw = w[c], lb = bb[c];
    float ya = (va - muA) * rsqrtf(varA + 1e-6f) * lw + lb;
    float yb = (vb - muB) * rsqrtf(varB + 1e-6f) * lw + lb;
    float xo = x[(size_t)row * DIMC + c];
    out[(size_t)row * DIMC + c] = xo + ya + yb;
}

extern "C" void kernel_launch(void* const* d_in, const int* in_sizes, int n_in,
                              void* d_out, int out_size, void* d_ws, size_t ws_size,
                              hipStream_t stream) {
    const float* x      = (const float*)d_in[0];
    const float* ln1_w  = (const float*)d_in[1];
    const float* ln1_b  = (const float*)d_in[2];
    const float* ln2_w  = (const float*)d_in[3];
    const float* ln2_b  = (const float*)d_in[4];
    const float* W_in   = (const float*)d_in[5];
    const float* conv_w = (const float*)d_in[6];
    const float* conv_b = (const float*)d_in[7];
    const float* W_x    = (const float*)d_in[8];
    const float* W_dt   = (const float*)d_in[9];
    const float* b_dt   = (const float*)d_in[10];
    const float* A_log  = (const float*)d_in[11];
    const float* D_par  = (const float*)d_in[12];
    const float* W_out  = (const float*)d_in[13];
    float* out = (float*)d_out;

    // ---- workspace (~169 MB) ----
    char* ws = (char*)d_ws;
    size_t off = 0;
    ushort_t* wb_in  = (ushort_t*)(ws + off); off += (size_t)1024 * 256 * 2;
    ushort_t* wb_x   = (ushort_t*)(ws + off); off += (size_t)144 * 512 * 2;
    ushort_t* wb_out = (ushort_t*)(ws + off); off += (size_t)256 * 512 * 2;
    const size_t R0 = (size_t)MROWS * DIMC * 2;
    const size_t R1 = (size_t)MROWS * 512 * 2;
    ushort_t* r0 = (ushort_t*)(ws + off); off += R0;   // xm -> xdbl -> outm
    ushort_t* r1 = (ushort_t*)(ws + off); off += R1;   // xhalf -> dt_T
    ushort_t* r2 = (ushort_t*)(ws + off); off += R1;   // z
    ushort_t* r3 = (ushort_t*)(ws + off); off += R1;   // xc -> w_T -> ys
    ushort_t* r4 = (ushort_t*)(ws + off); off += R1;   // u_T -> ysT (in place)
    f32x4*    BCfI = (f32x4*)(ws + off);  off += (size_t)MROWS * 64 * 8;  // 16.8 MB

    ushort_t* xm    = r0;
    ushort_t* xdbl  = r0;
    ushort_t* outm  = r0;
    ushort_t* xhalf = r1;
    ushort_t* dt_T  = r1;
    ushort_t* zb    = r2;
    ushort_t* xc    = r3;
    ushort_t* w_T   = r3;
    ushort_t* ys    = r3;
    ushort_t* u_T   = r4;

    // 0. convert MFMA weights fp32 -> bf16 (one launch)
    const int ncvt = 1024 * 256 + 144 * 512 + 256 * 512;
    hipLaunchKernelGGL(cvtw3, dim3((ncvt + 255) / 256), dim3(256), 0, stream,
                       W_in, wb_in, W_x, wb_x, W_out, wb_out);

    // A. LayerNorm + dual-order xm
    hipLaunchKernelGGL(ln1_build_xm, dim3(4 * LSEQ), dim3(256), 0, stream,
                       x, ln1_w, ln1_b, xm);
    // B. one launch: cols<512 -> xhalf, cols>=512 -> zb
    hipLaunchKernelGGL(gemm128_split, dim3(MROWS / 128, 8), dim3(256), 0, stream,
                       xm, wb_in, xhalf, zb);
    // C. tiled conv + SiLU: xhalf -> xc[bt,d] + u_T[b,d,t]
    hipLaunchKernelGGL(conv_silu_t, dim3(MROWS / 64, 8), dim3(256), 0, stream,
                       xhalf, conv_w, conv_b, xc, u_T);
    // D. x_dbl = xc @ W_x^T   (N=144, K=512)
    hipLaunchKernelGGL(gemm128, dim3(MROWS / 128, 2), dim3(256), 0, stream,
                       xc, wb_x, xdbl, MROWS, 144, 512);
    // E. dt/w (+ pair-interleaved, state-permuted B/C unpack)
    hipLaunchKernelGGL(dt_sp_t, dim3(MROWS / 64, 8), dim3(256), 0, stream,
                       xdbl, W_dt, b_dt, u_T, dt_T, w_T, BCfI);
    // F. selective scan v16: u_T -> ysT in place
    hipLaunchKernelGGL(scan16, dim3(BS2 * 512 / 4), dim3(256), 0, stream,
                       dt_T, u_T, w_T, BCfI, A_log, D_par);
    // G. gate + transpose: ys[bt,d] = ysT * silu(z)
    hipLaunchKernelGGL(gate_t, dim3(MROWS / 64, 8), dim3(256), 0, stream,
                       u_T, zb, ys);
    // H. outm = ys @ W_out^T   (N=256, K=512)
    hipLaunchKernelGGL(gemm128, dim3(MROWS / 128, 2), dim3(256), 0, stream,
                       ys, wb_out, outm, MROWS, 256, 512);
    // I. final LN + transpose combine + residual (fp32 out)
    hipLaunchKernelGGL(final_ln_add, dim3(4 * LSEQ), dim3(256), 0, stream,
                       outm, x, ln2_w, ln2_b, out);
}